// Round 2
// baseline (311580.078 us; speedup 1.0000x reference)
//
#include <hip/hip_runtime.h>
#include <math.h>
#include <stdint.h>

#define TT 2048
#define BB 64
#define II 256
#define HH 512
#define EHD 128
#define NWG 144
#define GATEWG 128

typedef __attribute__((ext_vector_type(8))) short s16x8;
typedef __attribute__((ext_vector_type(4))) float f32x4;

// ---------------- helpers ----------------
__device__ __forceinline__ float dot4(const float4 a, const float4 b){
    return a.x*b.x + a.y*b.y + a.z*b.z + a.w*b.w;
}
__device__ __forceinline__ float sigm(float x){ return 1.0f/(1.0f+expf(-x)); }
__device__ __forceinline__ float leakyf(float x){ return x > 0.0f ? x : 0.01f*x; }
__device__ __forceinline__ float alphaf(float x){
    float p = 1.0f/(1.0f+expf(-x));
    return p/(1.0f-p);
}
__device__ __forceinline__ f32x4 MFMA(s16x8 a, s16x8 b, f32x4 c){
    return __builtin_amdgcn_mfma_f32_16x16x32_bf16(a, b, c, 0, 0, 0);
}

// global barrier: monotonic counter, 144 participants.
// __threadfence() at agent scope emits L2 writeback + invalidate on gfx950,
// giving cross-XCD release/acquire around the atomic counter.
__device__ __forceinline__ void gbar(int* bar, int target){
    __syncthreads();                       // all wg threads done (incl. vmcnt drain)
    if (threadIdx.x == 0){
        __threadfence();                   // release: flush dirty L2 (covers whole XCD)
        atomicAdd(bar, 1);
        while (__hip_atomic_load(bar, __ATOMIC_RELAXED, __HIP_MEMORY_SCOPE_AGENT) < target){
            __builtin_amdgcn_s_sleep(2);
        }
        __threadfence();                   // acquire: invalidate L1/L2
    }
    __syncthreads();
}

// ---------------- encoder block: 4 rows through the 3-layer MLP (fp32) ----------------
// smem: 4*516 + 2*4*132 = 3120 floats
__device__ void enc_h_block(int e, const float* __restrict__ hsrc,
                            float* __restrict__ htil,
                            const float* __restrict__ w1, const float* __restrict__ b1,
                            const float* __restrict__ w2, const float* __restrict__ b2,
                            const float* __restrict__ w3, const float* __restrict__ b3,
                            float* smem)
{
    float* hlds = smem;              // [4][516]
    float* t1   = smem + 4*516;      // [4][132]
    float* t2   = t1 + 4*132;        // [4][132]
    const int tid = threadIdx.x;
    const int r0 = e * 4;
    for (int i = 0; i < 8; i++){
        int el = tid + i*256;
        int rr = el >> 9, k = el & 511;
        hlds[rr*516 + k] = hsrc[(r0+rr)*HH + k];
    }
    __syncthreads();
    const int cc = tid & 63;
    const int rr = (tid >> 6) & 3;
    // layer 1: 512 -> 128, leaky (dual accumulators to halve dep chain)
    for (int cb = 0; cb < 2; cb++){
        int c = cc + cb*64;
        const float* wr = w1 + c*HH;
        const float* xr = hlds + rr*516;
        float a0 = b1[c], a1 = 0.f;
        #pragma unroll 8
        for (int k = 0; k < HH; k += 8){
            a0 += dot4(*(const float4*)(xr+k),   *(const float4*)(wr+k));
            a1 += dot4(*(const float4*)(xr+k+4), *(const float4*)(wr+k+4));
        }
        t1[rr*132 + c] = leakyf(a0 + a1);
    }
    __syncthreads();
    // layer 2: 128 -> 128, leaky
    for (int cb = 0; cb < 2; cb++){
        int c = cc + cb*64;
        const float* wr = w2 + c*EHD;
        const float* xr = t1 + rr*132;
        float a0 = b2[c], a1 = 0.f;
        #pragma unroll 4
        for (int k = 0; k < EHD; k += 8){
            a0 += dot4(*(const float4*)(xr+k),   *(const float4*)(wr+k));
            a1 += dot4(*(const float4*)(xr+k+4), *(const float4*)(wr+k+4));
        }
        t2[rr*132 + c] = leakyf(a0 + a1);
    }
    __syncthreads();
    // layer 3: 128 -> 512, alpha, scale by raw h
    for (int cb = 0; cb < 8; cb++){
        int c = cc + cb*64;
        const float* wr = w3 + c*EHD;
        const float* xr = t2 + rr*132;
        float a0 = b3[c], a1 = 0.f;
        #pragma unroll 4
        for (int k = 0; k < EHD; k += 8){
            a0 += dot4(*(const float4*)(xr+k),   *(const float4*)(wr+k));
            a1 += dot4(*(const float4*)(xr+k+4), *(const float4*)(wr+k+4));
        }
        float a = alphaf(a0 + a1);
        htil[(r0+rr)*HH + c] = hlds[rr*516 + c] * a;
    }
    __syncthreads();
}

__global__ __launch_bounds__(256) void enc_only_kernel(
    const float* __restrict__ hsrc, float* __restrict__ htil,
    const float* __restrict__ w1, const float* __restrict__ b1,
    const float* __restrict__ w2, const float* __restrict__ b2,
    const float* __restrict__ w3, const float* __restrict__ b3)
{
    __shared__ float smem[3120];
    enc_h_block(blockIdx.x, hsrc, htil, w1, b1, w2, b2, w3, b3, smem);
}

// ---------------- x' = input * alpha_y(input), all B*T rows (one-time) ----------------
__global__ __launch_bounds__(256) void ency_kernel(
    const float* __restrict__ xin, float* __restrict__ xprime,
    const float* __restrict__ w1, const float* __restrict__ b1,
    const float* __restrict__ w2, const float* __restrict__ b2,
    const float* __restrict__ w3, const float* __restrict__ b3)
{
    __shared__ float t1[32*128];
    __shared__ float t2[32*128];
    const long m0 = (long)blockIdx.x * 32;
    const int tid = threadIdx.x;
    const int cc = tid & 63;
    const int rr = tid >> 6;   // 0..3
    for (int cb = 0; cb < 2; cb++){
        int c = cc + cb*64;
        const float* wr = w1 + c*II;
        for (int q = 0; q < 8; q++){
            int r = rr*8 + q;
            const float* xr = xin + (m0 + r)*II;
            float a0 = b1[c], a1 = 0.f;
            #pragma unroll 8
            for (int k = 0; k < II; k += 8){
                a0 += dot4(*(const float4*)(xr+k),   *(const float4*)(wr+k));
                a1 += dot4(*(const float4*)(xr+k+4), *(const float4*)(wr+k+4));
            }
            t1[r*128 + c] = leakyf(a0 + a1);
        }
    }
    __syncthreads();
    for (int cb = 0; cb < 2; cb++){
        int c = cc + cb*64;
        const float* wr = w2 + c*EHD;
        for (int q = 0; q < 8; q++){
            int r = rr*8 + q;
            const float* xr = t1 + r*128;
            float a0 = b2[c], a1 = 0.f;
            #pragma unroll 4
            for (int k = 0; k < EHD; k += 8){
                a0 += dot4(*(const float4*)(xr+k),   *(const float4*)(wr+k));
                a1 += dot4(*(const float4*)(xr+k+4), *(const float4*)(wr+k+4));
            }
            t2[r*128 + c] = leakyf(a0 + a1);
        }
    }
    __syncthreads();
    for (int cb = 0; cb < 4; cb++){
        int c = cc + cb*64;
        const float* wr = w3 + c*EHD;
        for (int q = 0; q < 8; q++){
            int r = rr*8 + q;
            const float* xr = t2 + r*128;
            float a0 = b3[c], a1 = 0.f;
            #pragma unroll 4
            for (int k = 0; k < EHD; k += 8){
                a0 += dot4(*(const float4*)(xr+k),   *(const float4*)(wr+k));
                a1 += dot4(*(const float4*)(xr+k+4), *(const float4*)(wr+k+4));
            }
            float a = alphaf(a0 + a1);
            xprime[(m0 + r)*II + c] = xin[(m0 + r)*II + c] * a;
        }
    }
}

// ---------------- weight packing: bf16 hi/lo B-fragments ----------------
// layout (s16x8 units): [g 0..127][hl 0..1][kts 0..55][lane 0..63]
// kts 0..23 = layer0 (k: 0..255 Wih0, 256..767 Whh0), kts 24..55 = layer1
// fragment: col c = lane&15 -> n = (c>>2)*512 + g*4 + (c&3);  k = kt*32 + (lane>>4)*8 + j
__global__ __launch_bounds__(64) void prep_pack_kernel(
    const float* __restrict__ Wih0, const float* __restrict__ Whh0,
    const float* __restrict__ Wih1, const float* __restrict__ Whh1,
    ushort* __restrict__ wpack)
{
    const int b = blockIdx.x;          // 128*56 = 7168
    const int lane = threadIdx.x;      // 64
    const int g = b / 56, kts = b % 56;
    const int layer = (kts >= 24) ? 1 : 0;
    const int kt = layer ? (kts - 24) : kts;
    const int c = lane & 15;
    const int gate = c >> 2, uu = c & 3;
    const int n = gate*512 + g*4 + uu;
    const int k = kt*32 + (lane >> 4)*8;
    const float* src;
    if (!layer){
        if (k < 256) src = Wih0 + (long)n*II + k;
        else         src = Whh0 + (long)n*HH + (k - 256);
    } else {
        if (k < 512) src = Wih1 + (long)n*HH + k;
        else         src = Whh1 + (long)n*HH + (k - 512);
    }
    ushort hi[8], lo[8];
    #pragma unroll
    for (int j = 0; j < 8; j++){
        float v = src[j];
        uint32_t u = __float_as_uint(v);
        hi[j] = (ushort)(u >> 16);                           // truncation split
        float hf = __uint_as_float(u & 0xFFFF0000u);
        lo[j] = (ushort)(__float_as_uint(v - hf) >> 16);
    }
    long bhi = ((long)g*7168 + kts*64 + lane) * 8;
    long blo = bhi + (long)3584*8;
    #pragma unroll
    for (int j = 0; j < 8; j++){ wpack[bhi + j] = hi[j]; wpack[blo + j] = lo[j]; }
}

// ---------------- init ----------------
__global__ __launch_bounds__(256) void init_state_kernel(
    const float* __restrict__ h0, const float* __restrict__ c0,
    float* __restrict__ h_st, float* __restrict__ c_st, int* __restrict__ bar)
{
    int i = blockIdx.x*256 + threadIdx.x;   // 65536
    h_st[i] = h0[i];
    c_st[i] = c0[i];
    if (i == 0) bar[0] = 0;
}

// ---------------- gate phase: MFMA bf16x3 GEMM + pointwise ----------------
__device__ __forceinline__ void gate_phase(
    int phase, int t, int g, int tid,
    const s16x8* __restrict__ whl, s16x8* __restrict__ astage, float* __restrict__ glds,
    const s16x8* __restrict__ wp_lo,
    const float* __restrict__ xprime,
    const float* __restrict__ src_h0, const float* __restrict__ src_htil,
    const float* bsum,
    float* __restrict__ c_st, float* __restrict__ h_st,
    float* __restrict__ yout)
{
    const int lane = tid & 63;
    const int wv   = tid >> 6;              // wave id = M-tile it computes & stages
    const int brow = wv*16 + (lane & 15);   // staging source row
    const int kq   = lane >> 4;             // 0..3
    f32x4 acc1 = {0.f,0.f,0.f,0.f};
    f32x4 acc2 = {0.f,0.f,0.f,0.f};
    const int nch = phase ? 4 : 3;
    for (int ch = 0; ch < nch; ch++){
        // -------- stage [64 rows x 256 k] fp32 -> hi/lo A-fragments --------
        const float* p;
        if (phase == 0){
            if (ch == 0) p = xprime + ((long)brow*TT + t)*II;
            else         p = src_htil + (long)brow*HH + (ch-1)*256;
        } else {
            if (ch < 2)  p = src_h0  + (long)brow*HH + ch*256;
            else         p = src_htil + (long)brow*HH + (ch-2)*256;
        }
        #pragma unroll
        for (int o = 0; o < 8; o++){
            const float* q = p + (o*4 + kq)*8;
            float4 v0 = *(const float4*)q;
            float4 v1 = *(const float4*)(q+4);
            uint32_t u0 = __float_as_uint(v0.x), u1 = __float_as_uint(v0.y);
            uint32_t u2 = __float_as_uint(v0.z), u3 = __float_as_uint(v0.w);
            uint32_t u4 = __float_as_uint(v1.x), u5 = __float_as_uint(v1.y);
            uint32_t u6 = __float_as_uint(v1.z), u7 = __float_as_uint(v1.w);
            uint4 hi, lo;
            hi.x = (u0>>16) | (u1 & 0xFFFF0000u);
            hi.y = (u2>>16) | (u3 & 0xFFFF0000u);
            hi.z = (u4>>16) | (u5 & 0xFFFF0000u);
            hi.w = (u6>>16) | (u7 & 0xFFFF0000u);
            float l0 = v0.x - __uint_as_float(u0 & 0xFFFF0000u);
            float l1 = v0.y - __uint_as_float(u1 & 0xFFFF0000u);
            float l2 = v0.z - __uint_as_float(u2 & 0xFFFF0000u);
            float l3 = v0.w - __uint_as_float(u3 & 0xFFFF0000u);
            float l4 = v1.x - __uint_as_float(u4 & 0xFFFF0000u);
            float l5 = v1.y - __uint_as_float(u5 & 0xFFFF0000u);
            float l6 = v1.z - __uint_as_float(u6 & 0xFFFF0000u);
            float l7 = v1.w - __uint_as_float(u7 & 0xFFFF0000u);
            lo.x = (__float_as_uint(l0)>>16) | (__float_as_uint(l1) & 0xFFFF0000u);
            lo.y = (__float_as_uint(l2)>>16) | (__float_as_uint(l3) & 0xFFFF0000u);
            lo.z = (__float_as_uint(l4)>>16) | (__float_as_uint(l5) & 0xFFFF0000u);
            lo.w = (__float_as_uint(l6)>>16) | (__float_as_uint(l7) & 0xFFFF0000u);
            const int blk = (wv*8 + o)*64 + lane;   // frag slot: kt=o, A row=lane&15, k-grp=lane>>4
            ((uint4*)astage)[blk]        = hi;
            ((uint4*)astage)[2048 + blk] = lo;
        }
        __syncthreads();
        // -------- MFMA over 8 k-tiles --------
        const s16x8* ah = astage + wv*512;
        const s16x8* al = astage + 2048 + wv*512;
        const int ktg0 = (phase ? 24 : 0) + ch*8;
        #pragma unroll
        for (int ks = 0; ks < 8; ks++){
            s16x8 A1 = ah[ks*64 + lane];
            s16x8 A2 = al[ks*64 + lane];
            s16x8 B1 = whl[(ktg0+ks)*64 + lane];
            s16x8 B2 = wp_lo[(ktg0+ks)*64 + lane];
            acc1 = MFMA(A1, B1, acc1);   // hi*hi
            acc2 = MFMA(A2, B1, acc2);   // lo*hi
            acc2 = MFMA(A1, B2, acc2);   // hi*lo
        }
        __syncthreads();
    }
    f32x4 acc = acc1 + acc2;
    // -------- pointwise via LDS exchange --------
    {
        const int r0 = wv*16 + (lane>>4)*4;   // C frag: row=(lane>>4)*4+reg, col=lane&15
        const int cc = lane & 15;
        #pragma unroll
        for (int i2 = 0; i2 < 4; i2++) glds[(r0+i2)*17 + cc] = acc[i2];
    }
    __syncthreads();
    {
        const int pb = tid >> 2, puu = tid & 3;
        float gi = glds[pb*17 + 0  + puu] + bsum[0];
        float gf = glds[pb*17 + 4  + puu] + bsum[1];
        float gg = glds[pb*17 + 8  + puu] + bsum[2];
        float go = glds[pb*17 + 12 + puu] + bsum[3];
        const int j = g*4 + puu;
        float cold = c_st[pb*HH + j];
        float cn = sigm(gf)*cold + sigm(gi)*tanhf(gg);
        float hn = sigm(go)*tanhf(cn);
        c_st[pb*HH + j] = cn;
        h_st[pb*HH + j] = hn;
        if (yout) yout[((long)pb*TT + t)*HH + j] = hn;
    }
    __syncthreads();
}

// ---------------- persistent kernel ----------------
// wgs 0..127: gates (MFMA). wgs 128..143: encoder (fp32). 2 global barriers / step.
// dynamic LDS: whl 3584*16 + astage 4096*16 + glds 64*17*4 = 127232 B
__global__ __launch_bounds__(256, 1) void persistent_kernel(
    const float* __restrict__ xprime,
    float* __restrict__ h_st, float* __restrict__ c_st, float* __restrict__ htil,
    const ushort* __restrict__ wpack,
    const float* __restrict__ bih0, const float* __restrict__ bhh0,
    const float* __restrict__ bih1, const float* __restrict__ bhh1,
    const float* __restrict__ ehw1, const float* __restrict__ ehb1,
    const float* __restrict__ ehw2, const float* __restrict__ ehb2,
    const float* __restrict__ ehw3, const float* __restrict__ ehb3,
    float* __restrict__ out, int* __restrict__ bar)
{
    extern __shared__ char smem_raw[];
    const int wg = blockIdx.x, tid = threadIdx.x;
    if (wg >= NWG) return;
    float* h0_st = h_st;          float* h1_st = h_st + 32768;
    float* c0_st = c_st;          float* c1_st = c_st + 32768;
    float* htil0 = htil;          float* htil1 = htil + 32768;

    if (wg >= GATEWG){
        // ---------------- encoder workgroup ----------------
        float* smem = (float*)smem_raw;
        const int e = wg - GATEWG;
        for (int t = 0; t < TT; t++){
            enc_h_block(e, h1_st, htil1, ehw1, ehb1, ehw2, ehb2, ehw3, ehb3, smem);
            gbar(bar, NWG*(2*t+1));
            enc_h_block(e, h0_st, htil0, ehw1, ehb1, ehw2, ehb2, ehw3, ehb3, smem);
            gbar(bar, NWG*(2*t+2));
        }
        return;
    }
    // ---------------- gate workgroup ----------------
    s16x8* whl    = (s16x8*)smem_raw;          // 3584 frags (hi weights, both layers)
    s16x8* astage = whl + 3584;                // 4096 frags (A hi/lo, one 256-k chunk)
    float* glds   = (float*)(astage + 4096);   // 64*17 floats

    const int g = wg;
    const s16x8* wp_hi = ((const s16x8*)wpack) + (long)g*7168;
    const s16x8* wp_lo = wp_hi + 3584;
    for (int i = tid; i < 3584; i += 256) whl[i] = wp_hi[i];

    const int puu = tid & 3;
    float bsum0[4], bsum1[4];
    #pragma unroll
    for (int gate = 0; gate < 4; gate++){
        int n = gate*512 + g*4 + puu;
        bsum0[gate] = bih0[n] + bhh0[n];
        bsum1[gate] = bih1[n] + bhh1[n];
    }
    __syncthreads();

    for (int t = 0; t < TT; t++){
        gate_phase(0, t, g, tid, whl, astage, glds, wp_lo,
                   xprime, h0_st, htil0, bsum0, c0_st, h0_st, nullptr);
        gbar(bar, NWG*(2*t+1));
        gate_phase(1, t, g, tid, whl, astage, glds, wp_lo,
                   xprime, h0_st, htil1, bsum1, c1_st, h1_st, out);
        gbar(bar, NWG*(2*t+2));
    }
    // epilogue: h_n, c_n
    const long base = (long)BB*TT*HH;
    for (int i = wg*256 + tid; i < 65536; i += GATEWG*256){
        out[base + i]         = h_st[i];
        out[base + 65536 + i] = c_st[i];
    }
}

// ---------------- launch ----------------
extern "C" void kernel_launch(void* const* d_in, const int* in_sizes, int n_in,
                              void* d_out, int out_size, void* d_ws, size_t ws_size,
                              hipStream_t stream)
{
    const float* input = (const float*)d_in[0];
    const float* h0in  = (const float*)d_in[1];
    const float* c0in  = (const float*)d_in[2];
    const float* Wih0  = (const float*)d_in[3];
    const float* Whh0  = (const float*)d_in[4];
    const float* bih0  = (const float*)d_in[5];
    const float* bhh0  = (const float*)d_in[6];
    const float* Wih1  = (const float*)d_in[7];
    const float* Whh1  = (const float*)d_in[8];
    const float* bih1  = (const float*)d_in[9];
    const float* bhh1  = (const float*)d_in[10];
    const float* eyw1  = (const float*)d_in[11];
    const float* eyb1  = (const float*)d_in[12];
    const float* eyw2  = (const float*)d_in[13];
    const float* eyb2  = (const float*)d_in[14];
    const float* eyw3  = (const float*)d_in[15];
    const float* eyb3  = (const float*)d_in[16];
    const float* ehw1  = (const float*)d_in[17];
    const float* ehb1  = (const float*)d_in[18];
    const float* ehw2  = (const float*)d_in[19];
    const float* ehb2  = (const float*)d_in[20];
    const float* ehw3  = (const float*)d_in[21];
    const float* ehb3  = (const float*)d_in[22];

    float* out = (float*)d_out;
    float* ws  = (float*)d_ws;

    // ws layout (floats)
    float*  xprime = ws;                         // 33,554,432
    float*  h_st   = ws + 33554432;              // 65,536
    float*  c_st   = ws + 33619968;              // 65,536
    float*  htil   = ws + 33685504;              // 65,536
    int*    bar    = (int*)(ws + 33751040);      // 64 floats reserved
    ushort* wpack  = (ushort*)(ws + 33751104);   // 14,680,064 B

    static bool attr_done = false;
    if (!attr_done){
        hipFuncSetAttribute((const void*)persistent_kernel,
                            hipFuncAttributeMaxDynamicSharedMemorySize, 131072);
        attr_done = true;
    }

    init_state_kernel<<<256, 256, 0, stream>>>(h0in, c0in, h_st, c_st, bar);
    prep_pack_kernel<<<128*56, 64, 0, stream>>>(Wih0, Whh0, Wih1, Whh1, wpack);
    ency_kernel<<<4096, 256, 0, stream>>>(input, xprime,
                                          eyw1, eyb1, eyw2, eyb2, eyw3, eyb3);
    enc_only_kernel<<<16, 256, 0, stream>>>(h_st, htil,
                                            ehw1, ehb1, ehw2, ehb2, ehw3, ehb3);
    persistent_kernel<<<NWG, 256, 131072, stream>>>(
        xprime, h_st, c_st, htil, wpack,
        bih0, bhh0, bih1, bhh1,
        ehw1, ehb1, ehw2, ehb2, ehw3, ehb3,
        out, bar);
}

// Round 3
// 279787.012 us; speedup vs baseline: 1.1136x; 1.1136x over previous
//
#include <hip/hip_runtime.h>
#include <math.h>
#include <stdint.h>

#define TT 2048
#define BB 64
#define II 256
#define HH 512
#define EHD 128
#define NGATE 64
#define NENC 16
#define NWG 80

typedef __attribute__((ext_vector_type(8))) short s16x8;
typedef __attribute__((ext_vector_type(4))) float f32x4;
typedef __attribute__((ext_vector_type(4))) uint32_t u32x4;

// ---------------- scalar helpers ----------------
__device__ __forceinline__ float dot4(const float4 a, const float4 b){
    return a.x*b.x + a.y*b.y + a.z*b.z + a.w*b.w;
}
__device__ __forceinline__ float sigm(float x){ return 1.0f/(1.0f+expf(-x)); }
__device__ __forceinline__ float leakyf(float x){ return x > 0.0f ? x : 0.01f*x; }
__device__ __forceinline__ float alphaf(float x){
    float p = 1.0f/(1.0f+expf(-x));
    return p/(1.0f-p);
}
__device__ __forceinline__ f32x4 MFMA(s16x8 a, s16x8 b, f32x4 c){
    return __builtin_amdgcn_mfma_f32_16x16x32_bf16(a, b, c, 0, 0, 0);
}

// ---------------- coherent (cross-XCD) access: sc1 ops, no cache invalidation ----------------
__device__ __forceinline__ uint32_t cld_u32(const uint32_t* p){
    return __hip_atomic_load(p, __ATOMIC_RELAXED, __HIP_MEMORY_SCOPE_AGENT);
}
__device__ __forceinline__ uint64_t cld_u64(const uint64_t* p){
    return __hip_atomic_load(p, __ATOMIC_RELAXED, __HIP_MEMORY_SCOPE_AGENT);
}
__device__ __forceinline__ void cst_u32(uint32_t* p, uint32_t v){
    __hip_atomic_store(p, v, __ATOMIC_RELAXED, __HIP_MEMORY_SCOPE_AGENT);
}

// packed bf16 hi/lo pair: [hi16 | lo16], value ~= hi + lo (truncation split)
__device__ __forceinline__ uint32_t packsplit(float v){
    uint32_t u  = __float_as_uint(v);
    uint32_t hi = u & 0xFFFF0000u;
    float    lo = v - __uint_as_float(hi);
    return hi | (__float_as_uint(lo) >> 16);
}
__device__ __forceinline__ float unpackf(uint32_t w){
    return __uint_as_float(w & 0xFFFF0000u) + __uint_as_float(w << 16);
}

// ---------------- global barrier: NO fences, plain device-scope atomics ----------------
__device__ __forceinline__ void gbar(int* bar, int target){
    asm volatile("s_waitcnt vmcnt(0)" ::: "memory");   // this wave's coherent stores done
    __syncthreads();                                   // all waves of wg done
    if (threadIdx.x == 0){
        __hip_atomic_fetch_add(bar, 1, __ATOMIC_RELAXED, __HIP_MEMORY_SCOPE_AGENT);
        while (__hip_atomic_load(bar, __ATOMIC_RELAXED, __HIP_MEMORY_SCOPE_AGENT) < target)
            __builtin_amdgcn_s_sleep(1);
    }
    __syncthreads();
}

// ---------------- encoder block: 4 rows through the 3-layer MLP (fp32 math, packed I/O) ----------------
// smem: 4*516 + 2*4*132 = 3120 floats
__device__ void enc_h_block(int e, const uint32_t* __restrict__ hsrc,
                            uint32_t* __restrict__ htil,
                            const float* __restrict__ w1, const float* __restrict__ b1,
                            const float* __restrict__ w2, const float* __restrict__ b2,
                            const float* __restrict__ w3, const float* __restrict__ b3,
                            float* smem)
{
    float* hlds = smem;              // [4][516]
    float* t1   = smem + 4*516;      // [4][132]
    float* t2   = t1 + 4*132;        // [4][132]
    const int tid = threadIdx.x;
    const int r0 = e * 4;
    #pragma unroll
    for (int i = 0; i < 8; i++){
        int el = tid + i*256;
        int rr = el >> 9, k = el & 511;
        hlds[rr*516 + k] = unpackf(cld_u32(hsrc + (r0+rr)*HH + k));
    }
    __syncthreads();
    const int cc = tid & 63;
    const int rr = (tid >> 6) & 3;
    // layer 1: 512 -> 128, leaky
    for (int cb = 0; cb < 2; cb++){
        int c = cc + cb*64;
        const float* wr = w1 + c*HH;
        const float* xr = hlds + rr*516;
        float a0 = b1[c], a1 = 0.f;
        #pragma unroll 8
        for (int k = 0; k < HH; k += 8){
            a0 += dot4(*(const float4*)(xr+k),   *(const float4*)(wr+k));
            a1 += dot4(*(const float4*)(xr+k+4), *(const float4*)(wr+k+4));
        }
        t1[rr*132 + c] = leakyf(a0 + a1);
    }
    __syncthreads();
    // layer 2: 128 -> 128, leaky
    for (int cb = 0; cb < 2; cb++){
        int c = cc + cb*64;
        const float* wr = w2 + c*EHD;
        const float* xr = t1 + rr*132;
        float a0 = b2[c], a1 = 0.f;
        #pragma unroll 4
        for (int k = 0; k < EHD; k += 8){
            a0 += dot4(*(const float4*)(xr+k),   *(const float4*)(wr+k));
            a1 += dot4(*(const float4*)(xr+k+4), *(const float4*)(wr+k+4));
        }
        t2[rr*132 + c] = leakyf(a0 + a1);
    }
    __syncthreads();
    // layer 3: 128 -> 512, alpha, scale by raw h, coherent packed store
    for (int cb = 0; cb < 8; cb++){
        int c = cc + cb*64;
        const float* wr = w3 + c*EHD;
        const float* xr = t2 + rr*132;
        float a0 = b3[c], a1 = 0.f;
        #pragma unroll 4
        for (int k = 0; k < EHD; k += 8){
            a0 += dot4(*(const float4*)(xr+k),   *(const float4*)(wr+k));
            a1 += dot4(*(const float4*)(xr+k+4), *(const float4*)(wr+k+4));
        }
        float a = alphaf(a0 + a1);
        cst_u32(htil + (r0+rr)*HH + c, packsplit(hlds[rr*516 + c] * a));
    }
    __syncthreads();
}

__global__ __launch_bounds__(256) void enc_only_kernel(
    const uint32_t* __restrict__ hsrc, uint32_t* __restrict__ htil,
    const float* __restrict__ w1, const float* __restrict__ b1,
    const float* __restrict__ w2, const float* __restrict__ b2,
    const float* __restrict__ w3, const float* __restrict__ b3)
{
    __shared__ float smem[3120];
    enc_h_block(blockIdx.x, hsrc, htil, w1, b1, w2, b2, w3, b3, smem);
}

// ---------------- x' = input * alpha_y(input): packed, transposed to [T][B][I] ----------------
__global__ __launch_bounds__(256) void ency_kernel(
    const float* __restrict__ xin, uint32_t* __restrict__ xprime,
    const float* __restrict__ w1, const float* __restrict__ b1,
    const float* __restrict__ w2, const float* __restrict__ b2,
    const float* __restrict__ w3, const float* __restrict__ b3)
{
    __shared__ float t1[32*128];
    __shared__ float t2[32*128];
    const long m0 = (long)blockIdx.x * 32;
    const int tid = threadIdx.x;
    const int cc = tid & 63;
    const int rr = tid >> 6;   // 0..3
    for (int cb = 0; cb < 2; cb++){
        int c = cc + cb*64;
        const float* wr = w1 + c*II;
        for (int q = 0; q < 8; q++){
            int r = rr*8 + q;
            const float* xr = xin + (m0 + r)*II;
            float a0 = b1[c], a1 = 0.f;
            #pragma unroll 8
            for (int k = 0; k < II; k += 8){
                a0 += dot4(*(const float4*)(xr+k),   *(const float4*)(wr+k));
                a1 += dot4(*(const float4*)(xr+k+4), *(const float4*)(wr+k+4));
            }
            t1[r*128 + c] = leakyf(a0 + a1);
        }
    }
    __syncthreads();
    for (int cb = 0; cb < 2; cb++){
        int c = cc + cb*64;
        const float* wr = w2 + c*EHD;
        for (int q = 0; q < 8; q++){
            int r = rr*8 + q;
            const float* xr = t1 + r*128;
            float a0 = b2[c], a1 = 0.f;
            #pragma unroll 4
            for (int k = 0; k < EHD; k += 8){
                a0 += dot4(*(const float4*)(xr+k),   *(const float4*)(wr+k));
                a1 += dot4(*(const float4*)(xr+k+4), *(const float4*)(wr+k+4));
            }
            t2[r*128 + c] = leakyf(a0 + a1);
        }
    }
    __syncthreads();
    for (int cb = 0; cb < 4; cb++){
        int c = cc + cb*64;
        const float* wr = w3 + c*EHD;
        for (int q = 0; q < 8; q++){
            int r = rr*8 + q;
            const float* xr = t2 + r*128;
            float a0 = b3[c], a1 = 0.f;
            #pragma unroll 4
            for (int k = 0; k < EHD; k += 8){
                a0 += dot4(*(const float4*)(xr+k),   *(const float4*)(wr+k));
                a1 += dot4(*(const float4*)(xr+k+4), *(const float4*)(wr+k+4));
            }
            float a = alphaf(a0 + a1);
            long m = m0 + r;                       // m = b*TT + t
            long b = m >> 11, t = m & 2047;
            xprime[((long)t*BB + b)*II + c] = packsplit(xin[m*II + c] * a);
        }
    }
}

// ---------------- weight packing: bf16 hi/lo B-fragments (per 4-col group) ----------------
// frag: col c = lane&15 -> n = (c>>2)*512 + g4*4 + (c&3);  k = kt*32 + (lane>>4)*8 + j
// kts 0..23 = layer0 (k: 0..255 Wih0, 256..767 Whh0), kts 24..55 = layer1
__global__ __launch_bounds__(64) void prep_pack_kernel(
    const float* __restrict__ Wih0, const float* __restrict__ Whh0,
    const float* __restrict__ Wih1, const float* __restrict__ Whh1,
    ushort* __restrict__ wpack)
{
    const int b = blockIdx.x;          // 128*56 = 7168
    const int lane = threadIdx.x;      // 64
    const int g4 = b / 56, kts = b % 56;
    const int layer = (kts >= 24) ? 1 : 0;
    const int kt = layer ? (kts - 24) : kts;
    const int c = lane & 15;
    const int gate = c >> 2, uu = c & 3;
    const int n = gate*512 + g4*4 + uu;
    const int k = kt*32 + (lane >> 4)*8;
    const float* src;
    if (!layer){
        if (k < 256) src = Wih0 + (long)n*II + k;
        else         src = Whh0 + (long)n*HH + (k - 256);
    } else {
        if (k < 512) src = Wih1 + (long)n*HH + k;
        else         src = Whh1 + (long)n*HH + (k - 512);
    }
    ushort hi[8], lo[8];
    #pragma unroll
    for (int j = 0; j < 8; j++){
        float v = src[j];
        uint32_t u = __float_as_uint(v);
        hi[j] = (ushort)(u >> 16);
        float hf = __uint_as_float(u & 0xFFFF0000u);
        lo[j] = (ushort)(__float_as_uint(v - hf) >> 16);
    }
    long bhi = ((long)g4*7168 + kts*64 + lane) * 8;
    long blo = bhi + (long)3584*8;
    #pragma unroll
    for (int j = 0; j < 8; j++){ wpack[bhi + j] = hi[j]; wpack[blo + j] = lo[j]; }
}

// ---------------- init: pack h0 state ----------------
__global__ __launch_bounds__(256) void init_state_kernel(
    const float* __restrict__ h0, uint32_t* __restrict__ hpack, int* __restrict__ bar)
{
    int i = blockIdx.x*256 + threadIdx.x;   // 65536 (both layers)
    hpack[i] = packsplit(h0[i]);
    if (i == 0) bar[0] = 0;
}

// ---------------- A-fragment build from packed u64 pairs ----------------
__device__ __forceinline__ void mk_frag(const uint64_t d[4], s16x8* hi, s16x8* lo){
    union { u32x4 u; s16x8 s; } H, L;
    #pragma unroll
    for (int i = 0; i < 4; i++){
        uint32_t x0 = (uint32_t)d[i], x1 = (uint32_t)(d[i] >> 32);
        H.u[i] = __builtin_amdgcn_perm(x1, x0, 0x07060302u);  // [hi(k0)|hi(k1)]
        L.u[i] = __builtin_amdgcn_perm(x1, x0, 0x05040100u);  // [lo(k0)|lo(k1)]
    }
    *hi = H.s; *lo = L.s;
}

struct Accs { f32x4 a1, a2, b1, b2; };

__device__ __forceinline__ void do_chunk(const s16x8* whl,
                                         const s16x8* __restrict__ wlo0,
                                         const s16x8* __restrict__ wlo1,
                                         int ktg0, int lane,
                                         const s16x8 ahi[8], const s16x8 alo[8], Accs& ac)
{
    #pragma unroll
    for (int ks = 0; ks < 8; ks++){
        s16x8 B1a = whl[(ktg0+ks)*64 + lane];
        s16x8 B1b = whl[3584 + (ktg0+ks)*64 + lane];
        s16x8 B2a = wlo0[(ktg0+ks)*64 + lane];
        s16x8 B2b = wlo1[(ktg0+ks)*64 + lane];
        ac.a1 = MFMA(ahi[ks], B1a, ac.a1);
        ac.a2 = MFMA(alo[ks], B1a, ac.a2);
        ac.a2 = MFMA(ahi[ks], B2a, ac.a2);
        ac.b1 = MFMA(ahi[ks], B1b, ac.b1);
        ac.b2 = MFMA(alo[ks], B1b, ac.b2);
        ac.b2 = MFMA(ahi[ks], B2b, ac.b2);
    }
}

// ---------------- one gate phase: GEMM (A in regs) + pointwise ----------------
__device__ __forceinline__ void gate_phase(
    int phase, int t, int g, int tid,
    const s16x8* whl, float* glds,
    const s16x8* __restrict__ wlo0, const s16x8* __restrict__ wlo1,
    const uint32_t* __restrict__ xp,     // packed x' [T][B][I] (phase0)
    const uint32_t* __restrict__ h0p,    // packed h0 (phase1)
    const uint32_t* __restrict__ htilp,  // packed htil (this layer)
    const float* bsum,
    uint32_t* __restrict__ hdst,
    float creg[2], float hreg[2],
    float* __restrict__ yout)
{
    const int lane = tid & 63;
    const int wv   = tid >> 6;
    const int brow = wv*16 + (lane & 15);
    const int kq   = lane >> 4;
    Accs ac = {};
    s16x8 ahi[8], alo[8];
    if (phase == 0){
        {   // ch0: x' (normal cached loads, contiguous per t)
            const uint64_t* p = (const uint64_t*)(xp + ((long)t*BB + brow)*II) + kq*4;
            #pragma unroll
            for (int o = 0; o < 8; o++){
                uint64_t d[4];
                #pragma unroll
                for (int i = 0; i < 4; i++) d[i] = p[o*16 + i];
                mk_frag(d, &ahi[o], &alo[o]);
            }
            do_chunk(whl, wlo0, wlo1, 0, lane, ahi, alo, ac);
        }
        #pragma unroll
        for (int ch = 1; ch < 3; ch++){   // ch1,2: htil0 (coherent)
            const uint64_t* p = (const uint64_t*)(htilp + (long)brow*HH + (ch-1)*256) + kq*4;
            #pragma unroll
            for (int o = 0; o < 8; o++){
                uint64_t d[4];
                #pragma unroll
                for (int i = 0; i < 4; i++) d[i] = cld_u64(p + o*16 + i);
                mk_frag(d, &ahi[o], &alo[o]);
            }
            do_chunk(whl, wlo0, wlo1, ch*8, lane, ahi, alo, ac);
        }
    } else {
        #pragma unroll
        for (int ch = 0; ch < 4; ch++){   // ch0,1: h0; ch2,3: htil1 (all coherent)
            const uint32_t* srcp = (ch < 2) ? h0p : htilp;
            const uint64_t* p = (const uint64_t*)(srcp + (long)brow*HH + (ch&1)*256) + kq*4;
            #pragma unroll
            for (int o = 0; o < 8; o++){
                uint64_t d[4];
                #pragma unroll
                for (int i = 0; i < 4; i++) d[i] = cld_u64(p + o*16 + i);
                mk_frag(d, &ahi[o], &alo[o]);
            }
            do_chunk(whl, wlo0, wlo1, 24 + ch*8, lane, ahi, alo, ac);
        }
    }
    // C exchange through LDS
    {
        f32x4 caf = ac.a1 + ac.a2;
        f32x4 cbf = ac.b1 + ac.b2;
        const int r0 = wv*16 + (lane>>4)*4;
        const int c16 = lane & 15;
        #pragma unroll
        for (int i = 0; i < 4; i++){
            glds[(r0+i)*33 + c16]      = caf[i];
            glds[(r0+i)*33 + 16 + c16] = cbf[i];
        }
    }
    __syncthreads();
    // pointwise: thread owns (b, jloc) for b in {bb, bb+32}
    {
        const int jloc = tid & 7, bb = tid >> 3;
        const int ng = jloc >> 2, uu = jloc & 3;
        const int jcol = g*8 + jloc;
        #pragma unroll
        for (int half = 0; half < 2; half++){
            int b = bb + half*32;
            float gi = glds[b*33 + ng*16 + 0  + uu] + bsum[0];
            float gf = glds[b*33 + ng*16 + 4  + uu] + bsum[1];
            float gg = glds[b*33 + ng*16 + 8  + uu] + bsum[2];
            float go = glds[b*33 + ng*16 + 12 + uu] + bsum[3];
            float cn = sigm(gf)*creg[half] + sigm(gi)*tanhf(gg);
            float hn = sigm(go)*tanhf(cn);
            creg[half] = cn; hreg[half] = hn;
            cst_u32(hdst + b*HH + jcol, packsplit(hn));
            if (yout) yout[((long)b*TT + t)*HH + jcol] = hn;
        }
    }
}

// ---------------- persistent kernel: 64 gate wgs + 16 encoder wgs, 2 barriers/step ----------------
__global__ __launch_bounds__(256, 1) void persistent_kernel(
    const uint32_t* __restrict__ xp,
    uint32_t* __restrict__ hpack,
    const ushort* __restrict__ wpack,
    const float* __restrict__ c0in,
    const float* __restrict__ bih0, const float* __restrict__ bhh0,
    const float* __restrict__ bih1, const float* __restrict__ bhh1,
    const float* __restrict__ ehw1, const float* __restrict__ ehb1,
    const float* __restrict__ ehw2, const float* __restrict__ ehb2,
    const float* __restrict__ ehw3, const float* __restrict__ ehb3,
    float* __restrict__ out, int* __restrict__ bar)
{
    extern __shared__ char smem_raw[];
    const int wg = blockIdx.x, tid = threadIdx.x;
    uint32_t* h0p = hpack;
    uint32_t* h1p = hpack + 32768;
    uint32_t* ht0 = hpack + 65536;
    uint32_t* ht1 = hpack + 98304;

    if (wg >= NGATE){
        // -------- encoder wg --------
        float* smem = (float*)smem_raw;
        const int e = wg - NGATE;
        for (int t = 0; t < TT; t++){
            enc_h_block(e, h1p, ht1, ehw1, ehb1, ehw2, ehb2, ehw3, ehb3, smem);
            gbar(bar, NWG*(2*t+1));
            enc_h_block(e, h0p, ht0, ehw1, ehb1, ehw2, ehb2, ehw3, ehb3, smem);
            gbar(bar, NWG*(2*t+2));
        }
        return;
    }
    // -------- gate wg: 32 gate-columns (two 4-col groups 2g, 2g+1) --------
    s16x8* whl  = (s16x8*)smem_raw;          // [2][56][64] hi-weight frags = 114688 B
    float* glds = (float*)(whl + 7168);      // 64*33 floats
    const int g = wg;
    const s16x8* wp = (const s16x8*)wpack;
    for (int i = tid; i < 7168; i += 256){
        int ng = (i >= 3584) ? 1 : 0;
        int r  = i - ng*3584;
        whl[i] = wp[(long)(2*g+ng)*7168 + r];
    }
    const s16x8* wlo0 = wp + (long)(2*g  )*7168 + 3584;
    const s16x8* wlo1 = wp + (long)(2*g+1)*7168 + 3584;

    const int jloc = tid & 7, bb = tid >> 3;
    const int jcol = g*8 + jloc;
    float bsum0[4], bsum1[4];
    #pragma unroll
    for (int q = 0; q < 4; q++){
        int n = q*512 + jcol;
        bsum0[q] = bih0[n] + bhh0[n];
        bsum1[q] = bih1[n] + bhh1[n];
    }
    float c0reg[2], c1reg[2], h0reg[2] = {0.f,0.f}, h1reg[2] = {0.f,0.f};
    #pragma unroll
    for (int half = 0; half < 2; half++){
        int b = bb + half*32;
        c0reg[half] = c0in[b*HH + jcol];
        c1reg[half] = c0in[32768 + b*HH + jcol];
    }
    __syncthreads();

    for (int t = 0; t < TT; t++){
        gate_phase(0, t, g, tid, whl, glds, wlo0, wlo1,
                   xp, h0p, ht0, bsum0, h0p, c0reg, h0reg, nullptr);
        gbar(bar, NWG*(2*t+1));
        gate_phase(1, t, g, tid, whl, glds, wlo0, wlo1,
                   xp, h0p, ht1, bsum1, h1p, c1reg, h1reg, out);
        gbar(bar, NWG*(2*t+2));
    }
    // tails from registers (normal stores; kernel-end flush)
    const long base = (long)BB*TT*HH;
    #pragma unroll
    for (int half = 0; half < 2; half++){
        int b = bb + half*32;
        out[base +             b*HH + jcol] = h0reg[half];
        out[base + 32768     + b*HH + jcol] = h1reg[half];
        out[base + 65536     + b*HH + jcol] = c0reg[half];
        out[base + 65536 + 32768 + b*HH + jcol] = c1reg[half];
    }
}

// ---------------- launch ----------------
extern "C" void kernel_launch(void* const* d_in, const int* in_sizes, int n_in,
                              void* d_out, int out_size, void* d_ws, size_t ws_size,
                              hipStream_t stream)
{
    const float* input = (const float*)d_in[0];
    const float* h0in  = (const float*)d_in[1];
    const float* c0in  = (const float*)d_in[2];
    const float* Wih0  = (const float*)d_in[3];
    const float* Whh0  = (const float*)d_in[4];
    const float* bih0  = (const float*)d_in[5];
    const float* bhh0  = (const float*)d_in[6];
    const float* Wih1  = (const float*)d_in[7];
    const float* Whh1  = (const float*)d_in[8];
    const float* bih1  = (const float*)d_in[9];
    const float* bhh1  = (const float*)d_in[10];
    const float* eyw1  = (const float*)d_in[11];
    const float* eyb1  = (const float*)d_in[12];
    const float* eyw2  = (const float*)d_in[13];
    const float* eyb2  = (const float*)d_in[14];
    const float* eyw3  = (const float*)d_in[15];
    const float* eyb3  = (const float*)d_in[16];
    const float* ehw1  = (const float*)d_in[17];
    const float* ehb1  = (const float*)d_in[18];
    const float* ehw2  = (const float*)d_in[19];
    const float* ehb2  = (const float*)d_in[20];
    const float* ehw3  = (const float*)d_in[21];
    const float* ehb3  = (const float*)d_in[22];

    float* out = (float*)d_out;
    float* ws  = (float*)d_ws;

    // ws layout (4B units)
    uint32_t* xprime = (uint32_t*)ws;                  // [T][B][I] packed, 33,554,432
    uint32_t* hpack  = (uint32_t*)(ws + 33554432);     // 4 x 32768 (h0,h1,ht0,ht1)
    int*      bar    = (int*)(ws + 33685504);          // own region
    ushort*   wpack  = (ushort*)(ws + 33751104);       // 14,680,064 B

    static bool attr_done = false;
    if (!attr_done){
        hipFuncSetAttribute((const void*)persistent_kernel,
                            hipFuncAttributeMaxDynamicSharedMemorySize, 131072);
        attr_done = true;
    }

    init_state_kernel<<<256, 256, 0, stream>>>(h0in, hpack, bar);
    prep_pack_kernel<<<128*56, 64, 0, stream>>>(Wih0, Whh0, Wih1, Whh1, wpack);
    ency_kernel<<<4096, 256, 0, stream>>>(input, xprime,
                                          eyw1, eyb1, eyw2, eyb2, eyw3, eyb3);
    enc_only_kernel<<<16, 256, 0, stream>>>(hpack, hpack + 65536,
                                            ehw1, ehb1, ehw2, ehb2, ehw3, ehb3);
    persistent_kernel<<<NWG, 256, 123200, stream>>>(
        xprime, hpack, wpack, c0in,
        bih0, bhh0, bih1, bhh1,
        ehw1, ehb1, ehw2, ehb2, ehw3, ehb3,
        out, bar);
}

// Round 4
// 208030.371 us; speedup vs baseline: 1.4978x; 1.3449x over previous
//
#include <hip/hip_runtime.h>
#include <math.h>
#include <stdint.h>

#define TT 2048
#define BB 64
#define II 256
#define HH 512
#define EHD 128
#define NGATE 64
#define NENC 4
#define NWG 68

typedef __attribute__((ext_vector_type(8))) short s16x8;
typedef __attribute__((ext_vector_type(4))) float f32x4;
typedef __attribute__((ext_vector_type(4))) uint32_t u32x4;

// ---------------- scalar helpers ----------------
__device__ __forceinline__ float dot4(const float4 a, const float4 b){
    return a.x*b.x + a.y*b.y + a.z*b.z + a.w*b.w;
}
__device__ __forceinline__ float sigm(float x){ return 1.0f/(1.0f+expf(-x)); }
__device__ __forceinline__ float leakyf(float x){ return x > 0.0f ? x : 0.01f*x; }
__device__ __forceinline__ float alphaf(float x){
    float p = 1.0f/(1.0f+expf(-x));
    return p/(1.0f-p);
}
__device__ __forceinline__ f32x4 MFMA(s16x8 a, s16x8 b, f32x4 c){
    return __builtin_amdgcn_mfma_f32_16x16x32_bf16(a, b, c, 0, 0, 0);
}

// ---------------- coherent (cross-XCD) access: sc1 ops, no cache invalidation ----------------
__device__ __forceinline__ uint32_t cld_u32(const uint32_t* p){
    return __hip_atomic_load(p, __ATOMIC_RELAXED, __HIP_MEMORY_SCOPE_AGENT);
}
__device__ __forceinline__ uint64_t cld_u64(const uint64_t* p){
    return __hip_atomic_load(p, __ATOMIC_RELAXED, __HIP_MEMORY_SCOPE_AGENT);
}
__device__ __forceinline__ void cst_u32(uint32_t* p, uint32_t v){
    __hip_atomic_store(p, v, __ATOMIC_RELAXED, __HIP_MEMORY_SCOPE_AGENT);
}

// packed bf16 hi/lo pair: [hi16 | lo16], value ~= hi + lo (truncation split)
__device__ __forceinline__ uint32_t packsplit(float v){
    uint32_t u  = __float_as_uint(v);
    uint32_t hi = u & 0xFFFF0000u;
    float    lo = v - __uint_as_float(hi);
    return hi | (__float_as_uint(lo) >> 16);
}
__device__ __forceinline__ float unpackf(uint32_t w){
    return __uint_as_float(w & 0xFFFF0000u) + __uint_as_float(w << 16);
}

// ---------------- global barrier: NO fences, plain device-scope atomics ----------------
__device__ __forceinline__ void gbar(int* bar, int target){
    asm volatile("s_waitcnt vmcnt(0)" ::: "memory");
    __syncthreads();
    if (threadIdx.x == 0){
        __hip_atomic_fetch_add(bar, 1, __ATOMIC_RELAXED, __HIP_MEMORY_SCOPE_AGENT);
        while (__hip_atomic_load(bar, __ATOMIC_RELAXED, __HIP_MEMORY_SCOPE_AGENT) < target)
            __builtin_amdgcn_s_sleep(1);
    }
    __syncthreads();
}

// ---------------- fragment builders ----------------
// A/B frag convention (proven in gate path):
//   A: row = lane&15, k = kt*32 + (lane>>4)*8 + j
//   B: col = lane&15, k = kt*32 + (lane>>4)*8 + j
//   C: col = lane&15, row = (lane>>4)*4 + reg
__device__ __forceinline__ void mk_frag(const uint64_t d[4], s16x8* hi, s16x8* lo){
    union { u32x4 u; s16x8 s; } H, L;
    #pragma unroll
    for (int i = 0; i < 4; i++){
        uint32_t x0 = (uint32_t)d[i], x1 = (uint32_t)(d[i] >> 32);
        H.u[i] = __builtin_amdgcn_perm(x1, x0, 0x07060302u);
        L.u[i] = __builtin_amdgcn_perm(x1, x0, 0x05040100u);
    }
    *hi = H.s; *lo = L.s;
}
__device__ __forceinline__ void pack8(const float* f, s16x8* hi, s16x8* lo){
    union { u32x4 u; s16x8 s; } H, L;
    #pragma unroll
    for (int i = 0; i < 4; i++){
        float a = f[2*i], b = f[2*i+1];
        uint32_t ua = __float_as_uint(a), ub = __float_as_uint(b);
        uint32_t ha = ua & 0xFFFF0000u, hb = ub & 0xFFFF0000u;
        H.u[i] = (ua >> 16) | hb;
        float la = a - __uint_as_float(ha), lb = b - __uint_as_float(hb);
        L.u[i] = (__float_as_uint(la) >> 16) | (__float_as_uint(lb) & 0xFFFF0000u);
    }
    *hi = H.s; *lo = L.s;
}

// ---------------- fp32 encoder block (PROLOGUE ONLY, 4 rows/block) ----------------
__device__ void enc_h_block(int e, const uint32_t* __restrict__ hsrc,
                            uint32_t* __restrict__ htil,
                            const float* __restrict__ w1, const float* __restrict__ b1,
                            const float* __restrict__ w2, const float* __restrict__ b2,
                            const float* __restrict__ w3, const float* __restrict__ b3,
                            float* smem)
{
    float* hlds = smem;              // [4][516]
    float* t1   = smem + 4*516;      // [4][132]
    float* t2   = t1 + 4*132;        // [4][132]
    const int tid = threadIdx.x;
    const int r0 = e * 4;
    #pragma unroll
    for (int i = 0; i < 8; i++){
        int el = tid + i*256;
        int rr = el >> 9, k = el & 511;
        hlds[rr*516 + k] = unpackf(cld_u32(hsrc + (r0+rr)*HH + k));
    }
    __syncthreads();
    const int cc = tid & 63;
    const int rr = (tid >> 6) & 3;
    for (int cb = 0; cb < 2; cb++){
        int c = cc + cb*64;
        const float* wr = w1 + c*HH;
        const float* xr = hlds + rr*516;
        float a0 = b1[c], a1 = 0.f;
        #pragma unroll 8
        for (int k = 0; k < HH; k += 8){
            a0 += dot4(*(const float4*)(xr+k),   *(const float4*)(wr+k));
            a1 += dot4(*(const float4*)(xr+k+4), *(const float4*)(wr+k+4));
        }
        t1[rr*132 + c] = leakyf(a0 + a1);
    }
    __syncthreads();
    for (int cb = 0; cb < 2; cb++){
        int c = cc + cb*64;
        const float* wr = w2 + c*EHD;
        const float* xr = t1 + rr*132;
        float a0 = b2[c], a1 = 0.f;
        #pragma unroll 4
        for (int k = 0; k < EHD; k += 8){
            a0 += dot4(*(const float4*)(xr+k),   *(const float4*)(wr+k));
            a1 += dot4(*(const float4*)(xr+k+4), *(const float4*)(wr+k+4));
        }
        t2[rr*132 + c] = leakyf(a0 + a1);
    }
    __syncthreads();
    for (int cb = 0; cb < 8; cb++){
        int c = cc + cb*64;
        const float* wr = w3 + c*EHD;
        const float* xr = t2 + rr*132;
        float a0 = b3[c], a1 = 0.f;
        #pragma unroll 4
        for (int k = 0; k < EHD; k += 8){
            a0 += dot4(*(const float4*)(xr+k),   *(const float4*)(wr+k));
            a1 += dot4(*(const float4*)(xr+k+4), *(const float4*)(wr+k+4));
        }
        float a = alphaf(a0 + a1);
        cst_u32(htil + (r0+rr)*HH + c, packsplit(hlds[rr*516 + c] * a));
    }
    __syncthreads();
}

__global__ __launch_bounds__(256) void enc_only_kernel(
    const uint32_t* __restrict__ hsrc, uint32_t* __restrict__ htil,
    const float* __restrict__ w1, const float* __restrict__ b1,
    const float* __restrict__ w2, const float* __restrict__ b2,
    const float* __restrict__ w3, const float* __restrict__ b3)
{
    __shared__ float smem[3120];
    enc_h_block(blockIdx.x, hsrc, htil, w1, b1, w2, b2, w3, b3, smem);
}

// ---------------- MFMA encoder (steady state): 16 rows/wg, waves split N ----------------
// frag indices in epack: w1: f = NT*16 + kt   (NT=0..7,  kt=0..15)  ->   0..127
//                        w2: f = 128 + NT*4+kt (NT=0..7,  kt=0..3)  -> 128..159
//                        w3: f = 160 + NT*4+kt (NT=0..31, kt=0..3)  -> 160..287
__device__ __forceinline__ void enc_mfma(
    int e, const uint32_t* __restrict__ hsrc, uint32_t* __restrict__ htil,
    const s16x8* __restrict__ ehi, const s16x8* __restrict__ elo,
    const float bias1[2], const float bias2[2], const float bias3[8],
    float* t1, float* t2)
{
    const int tid  = threadIdx.x;
    const int lane = tid & 63;
    const int wv   = tid >> 6;
    const int c16  = lane & 15;
    const int kq   = lane >> 4;
    const int r0   = e * 16;

    // ---- layer 1: [16,512] x w1^T -> t1[16,128] ----
    f32x4 p1[2] = {{0,0,0,0},{0,0,0,0}};
    f32x4 p2[2] = {{0,0,0,0},{0,0,0,0}};
    {
        const uint64_t* hp = (const uint64_t*)(hsrc + (long)(r0 + c16)*HH) + kq*4;
        #pragma unroll
        for (int kt = 0; kt < 16; kt++){
            uint64_t d[4];
            #pragma unroll
            for (int i = 0; i < 4; i++) d[i] = cld_u64(hp + kt*16 + i);
            s16x8 ah, al; mk_frag(d, &ah, &al);
            #pragma unroll
            for (int nt = 0; nt < 2; nt++){
                const int f = (wv*2 + nt)*16 + kt;
                s16x8 bh = ehi[f*64 + lane];
                s16x8 bl = elo[f*64 + lane];
                p1[nt] = MFMA(ah, bh, p1[nt]);
                p2[nt] = MFMA(al, bh, p2[nt]);
                p2[nt] = MFMA(ah, bl, p2[nt]);
            }
        }
    }
    #pragma unroll
    for (int nt = 0; nt < 2; nt++){
        f32x4 c = p1[nt] + p2[nt];
        const int n = wv*32 + nt*16 + c16;
        #pragma unroll
        for (int i = 0; i < 4; i++)
            t1[(kq*4 + i)*132 + n] = leakyf(c[i] + bias1[nt]);
    }
    __syncthreads();

    // ---- layer 2: t1 x w2^T -> t2[16,128] ----
    s16x8 a2h[4], a2l[4];
    #pragma unroll
    for (int kt = 0; kt < 4; kt++)
        pack8(t1 + c16*132 + kt*32 + kq*8, &a2h[kt], &a2l[kt]);
    f32x4 q1[2] = {{0,0,0,0},{0,0,0,0}};
    f32x4 q2[2] = {{0,0,0,0},{0,0,0,0}};
    #pragma unroll
    for (int kt = 0; kt < 4; kt++){
        #pragma unroll
        for (int nt = 0; nt < 2; nt++){
            const int f = 128 + (wv*2 + nt)*4 + kt;
            s16x8 bh = ehi[f*64 + lane];
            s16x8 bl = elo[f*64 + lane];
            q1[nt] = MFMA(a2h[kt], bh, q1[nt]);
            q2[nt] = MFMA(a2l[kt], bh, q2[nt]);
            q2[nt] = MFMA(a2h[kt], bl, q2[nt]);
        }
    }
    #pragma unroll
    for (int nt = 0; nt < 2; nt++){
        f32x4 c = q1[nt] + q2[nt];
        const int n = wv*32 + nt*16 + c16;
        #pragma unroll
        for (int i = 0; i < 4; i++)
            t2[(kq*4 + i)*132 + n] = leakyf(c[i] + bias2[nt]);
    }
    __syncthreads();

    // ---- layer 3: t2 x w3^T -> alpha; htil = h * alpha ----
    s16x8 a3h[4], a3l[4];
    #pragma unroll
    for (int kt = 0; kt < 4; kt++)
        pack8(t2 + c16*132 + kt*32 + kq*8, &a3h[kt], &a3l[kt]);
    #pragma unroll
    for (int nt = 0; nt < 8; nt++){
        f32x4 s1 = {0,0,0,0}, s2 = {0,0,0,0};
        #pragma unroll
        for (int kt = 0; kt < 4; kt++){
            const int f = 160 + (wv*8 + nt)*4 + kt;
            s16x8 bh = ehi[f*64 + lane];
            s16x8 bl = elo[f*64 + lane];
            s1 = MFMA(a3h[kt], bh, s1);
            s2 = MFMA(a3l[kt], bh, s2);
            s2 = MFMA(a3h[kt], bl, s2);
        }
        f32x4 c = s1 + s2;
        const int n = wv*128 + nt*16 + c16;
        #pragma unroll
        for (int i = 0; i < 4; i++){
            const int row = r0 + kq*4 + i;
            float a  = alphaf(c[i] + bias3[nt]);
            float hv = unpackf(cld_u32(hsrc + (long)row*HH + n));
            cst_u32(htil + (long)row*HH + n, packsplit(hv * a));
        }
    }
}

// ---------------- x' = input * alpha_y(input): packed, transposed to [T][B][I] ----------------
__global__ __launch_bounds__(256) void ency_kernel(
    const float* __restrict__ xin, uint32_t* __restrict__ xprime,
    const float* __restrict__ w1, const float* __restrict__ b1,
    const float* __restrict__ w2, const float* __restrict__ b2,
    const float* __restrict__ w3, const float* __restrict__ b3)
{
    __shared__ float t1[32*128];
    __shared__ float t2[32*128];
    const long m0 = (long)blockIdx.x * 32;
    const int tid = threadIdx.x;
    const int cc = tid & 63;
    const int rr = tid >> 6;
    for (int cb = 0; cb < 2; cb++){
        int c = cc + cb*64;
        const float* wr = w1 + c*II;
        for (int q = 0; q < 8; q++){
            int r = rr*8 + q;
            const float* xr = xin + (m0 + r)*II;
            float a0 = b1[c], a1 = 0.f;
            #pragma unroll 8
            for (int k = 0; k < II; k += 8){
                a0 += dot4(*(const float4*)(xr+k),   *(const float4*)(wr+k));
                a1 += dot4(*(const float4*)(xr+k+4), *(const float4*)(wr+k+4));
            }
            t1[r*128 + c] = leakyf(a0 + a1);
        }
    }
    __syncthreads();
    for (int cb = 0; cb < 2; cb++){
        int c = cc + cb*64;
        const float* wr = w2 + c*EHD;
        for (int q = 0; q < 8; q++){
            int r = rr*8 + q;
            const float* xr = t1 + r*128;
            float a0 = b2[c], a1 = 0.f;
            #pragma unroll 4
            for (int k = 0; k < EHD; k += 8){
                a0 += dot4(*(const float4*)(xr+k),   *(const float4*)(wr+k));
                a1 += dot4(*(const float4*)(xr+k+4), *(const float4*)(wr+k+4));
            }
            t2[r*128 + c] = leakyf(a0 + a1);
        }
    }
    __syncthreads();
    for (int cb = 0; cb < 4; cb++){
        int c = cc + cb*64;
        const float* wr = w3 + c*EHD;
        for (int q = 0; q < 8; q++){
            int r = rr*8 + q;
            const float* xr = t2 + r*128;
            float a0 = b3[c], a1 = 0.f;
            #pragma unroll 4
            for (int k = 0; k < EHD; k += 8){
                a0 += dot4(*(const float4*)(xr+k),   *(const float4*)(wr+k));
                a1 += dot4(*(const float4*)(xr+k+4), *(const float4*)(wr+k+4));
            }
            float a = alphaf(a0 + a1);
            long m = m0 + r;                       // m = b*TT + t
            long b = m >> 11, t = m & 2047;
            xprime[((long)t*BB + b)*II + c] = packsplit(xin[m*II + c] * a);
        }
    }
}

// ---------------- gate weight packing (unchanged, proven) ----------------
__global__ __launch_bounds__(64) void prep_pack_kernel(
    const float* __restrict__ Wih0, const float* __restrict__ Whh0,
    const float* __restrict__ Wih1, const float* __restrict__ Whh1,
    ushort* __restrict__ wpack)
{
    const int b = blockIdx.x;          // 128*56 = 7168
    const int lane = threadIdx.x;
    const int g4 = b / 56, kts = b % 56;
    const int layer = (kts >= 24) ? 1 : 0;
    const int kt = layer ? (kts - 24) : kts;
    const int c = lane & 15;
    const int gate = c >> 2, uu = c & 3;
    const int n = gate*512 + g4*4 + uu;
    const int k = kt*32 + (lane >> 4)*8;
    const float* src;
    if (!layer){
        if (k < 256) src = Wih0 + (long)n*II + k;
        else         src = Whh0 + (long)n*HH + (k - 256);
    } else {
        if (k < 512) src = Wih1 + (long)n*HH + k;
        else         src = Whh1 + (long)n*HH + (k - 512);
    }
    ushort hi[8], lo[8];
    #pragma unroll
    for (int j = 0; j < 8; j++){
        float v = src[j];
        uint32_t u = __float_as_uint(v);
        hi[j] = (ushort)(u >> 16);
        float hf = __uint_as_float(u & 0xFFFF0000u);
        lo[j] = (ushort)(__float_as_uint(v - hf) >> 16);
    }
    long bhi = ((long)g4*7168 + kts*64 + lane) * 8;
    long blo = bhi + (long)3584*8;
    #pragma unroll
    for (int j = 0; j < 8; j++){ wpack[bhi + j] = hi[j]; wpack[blo + j] = lo[j]; }
}

// ---------------- encoder weight packing (NEW) ----------------
__global__ __launch_bounds__(64) void enc_pack_kernel(
    const float* __restrict__ w1, const float* __restrict__ w2,
    const float* __restrict__ w3, ushort* __restrict__ epack)
{
    const int f = blockIdx.x;      // 0..287
    const int lane = threadIdx.x;
    const int c = lane & 15, kq = lane >> 4;
    const float* src;
    if (f < 128){
        int nt = f >> 4, kt = f & 15;
        src = w1 + (long)(nt*16 + c)*HH + kt*32 + kq*8;
    } else if (f < 160){
        int q = f - 128; int nt = q >> 2, kt = q & 3;
        src = w2 + (long)(nt*16 + c)*EHD + kt*32 + kq*8;
    } else {
        int q = f - 160; int nt = q >> 2, kt = q & 3;
        src = w3 + (long)(nt*16 + c)*EHD + kt*32 + kq*8;
    }
    long off = ((long)f*64 + lane)*8;
    #pragma unroll
    for (int j = 0; j < 8; j++){
        float v = src[j];
        uint32_t u = __float_as_uint(v);
        epack[off + j] = (ushort)(u >> 16);
        float hf = __uint_as_float(u & 0xFFFF0000u);
        epack[off + 147456 + j] = (ushort)(__float_as_uint(v - hf) >> 16);
    }
}

// ---------------- init: pack h0 state ----------------
__global__ __launch_bounds__(256) void init_state_kernel(
    const float* __restrict__ h0, uint32_t* __restrict__ hpack, int* __restrict__ bar)
{
    int i = blockIdx.x*256 + threadIdx.x;
    hpack[i] = packsplit(h0[i]);
    if (i == 0) bar[0] = 0;
}

// ---------------- gate GEMM pieces (unchanged, proven) ----------------
struct Accs { f32x4 a1, a2, b1, b2; };

__device__ __forceinline__ void do_chunk(const s16x8* whl,
                                         const s16x8* __restrict__ wlo0,
                                         const s16x8* __restrict__ wlo1,
                                         int ktg0, int lane,
                                         const s16x8 ahi[8], const s16x8 alo[8], Accs& ac)
{
    #pragma unroll
    for (int ks = 0; ks < 8; ks++){
        s16x8 B1a = whl[(ktg0+ks)*64 + lane];
        s16x8 B1b = whl[3584 + (ktg0+ks)*64 + lane];
        s16x8 B2a = wlo0[(ktg0+ks)*64 + lane];
        s16x8 B2b = wlo1[(ktg0+ks)*64 + lane];
        ac.a1 = MFMA(ahi[ks], B1a, ac.a1);
        ac.a2 = MFMA(alo[ks], B1a, ac.a2);
        ac.a2 = MFMA(ahi[ks], B2a, ac.a2);
        ac.b1 = MFMA(ahi[ks], B1b, ac.b1);
        ac.b2 = MFMA(alo[ks], B1b, ac.b2);
        ac.b2 = MFMA(ahi[ks], B2b, ac.b2);
    }
}

__device__ __forceinline__ void gate_phase(
    int phase, int t, int g, int tid,
    const s16x8* whl, float* glds,
    const s16x8* __restrict__ wlo0, const s16x8* __restrict__ wlo1,
    const uint32_t* __restrict__ xp,
    const uint32_t* __restrict__ h0p,
    const uint32_t* __restrict__ htilp,
    const float* bsum,
    uint32_t* __restrict__ hdst,
    float creg[2], float hreg[2],
    float* __restrict__ yout)
{
    const int lane = tid & 63;
    const int wv   = tid >> 6;
    const int brow = wv*16 + (lane & 15);
    const int kq   = lane >> 4;
    Accs ac = {};
    s16x8 ahi[8], alo[8];
    if (phase == 0){
        {
            const uint64_t* p = (const uint64_t*)(xp + ((long)t*BB + brow)*II) + kq*4;
            #pragma unroll
            for (int o = 0; o < 8; o++){
                uint64_t d[4];
                #pragma unroll
                for (int i = 0; i < 4; i++) d[i] = p[o*16 + i];
                mk_frag(d, &ahi[o], &alo[o]);
            }
            do_chunk(whl, wlo0, wlo1, 0, lane, ahi, alo, ac);
        }
        #pragma unroll
        for (int ch = 1; ch < 3; ch++){
            const uint64_t* p = (const uint64_t*)(htilp + (long)brow*HH + (ch-1)*256) + kq*4;
            #pragma unroll
            for (int o = 0; o < 8; o++){
                uint64_t d[4];
                #pragma unroll
                for (int i = 0; i < 4; i++) d[i] = cld_u64(p + o*16 + i);
                mk_frag(d, &ahi[o], &alo[o]);
            }
            do_chunk(whl, wlo0, wlo1, ch*8, lane, ahi, alo, ac);
        }
    } else {
        #pragma unroll
        for (int ch = 0; ch < 4; ch++){
            const uint32_t* srcp = (ch < 2) ? h0p : htilp;
            const uint64_t* p = (const uint64_t*)(srcp + (long)brow*HH + (ch&1)*256) + kq*4;
            #pragma unroll
            for (int o = 0; o < 8; o++){
                uint64_t d[4];
                #pragma unroll
                for (int i = 0; i < 4; i++) d[i] = cld_u64(p + o*16 + i);
                mk_frag(d, &ahi[o], &alo[o]);
            }
            do_chunk(whl, wlo0, wlo1, 24 + ch*8, lane, ahi, alo, ac);
        }
    }
    {
        f32x4 caf = ac.a1 + ac.a2;
        f32x4 cbf = ac.b1 + ac.b2;
        const int r0 = wv*16 + (lane>>4)*4;
        const int c16 = lane & 15;
        #pragma unroll
        for (int i = 0; i < 4; i++){
            glds[(r0+i)*33 + c16]      = caf[i];
            glds[(r0+i)*33 + 16 + c16] = cbf[i];
        }
    }
    __syncthreads();
    {
        const int jloc = tid & 7, bb = tid >> 3;
        const int ng = jloc >> 2, uu = jloc & 3;
        const int jcol = g*8 + jloc;
        #pragma unroll
        for (int half = 0; half < 2; half++){
            int b = bb + half*32;
            float gi = glds[b*33 + ng*16 + 0  + uu] + bsum[0];
            float gf = glds[b*33 + ng*16 + 4  + uu] + bsum[1];
            float gg = glds[b*33 + ng*16 + 8  + uu] + bsum[2];
            float go = glds[b*33 + ng*16 + 12 + uu] + bsum[3];
            float cn = sigm(gf)*creg[half] + sigm(gi)*tanhf(gg);
            float hn = sigm(go)*tanhf(cn);
            creg[half] = cn; hreg[half] = hn;
            cst_u32(hdst + b*HH + jcol, packsplit(hn));
            if (yout) yout[((long)b*TT + t)*HH + jcol] = hn;
        }
    }
    __syncthreads();
}

// ---------------- persistent kernel: 64 gate wgs + 4 MFMA-encoder wgs ----------------
__global__ __launch_bounds__(256, 1) void persistent_kernel(
    const uint32_t* __restrict__ xp,
    uint32_t* __restrict__ hpack,
    const ushort* __restrict__ wpack,
    const ushort* __restrict__ epack,
    const float* __restrict__ c0in,
    const float* __restrict__ bih0, const float* __restrict__ bhh0,
    const float* __restrict__ bih1, const float* __restrict__ bhh1,
    const float* __restrict__ ehb1, const float* __restrict__ ehb2,
    const float* __restrict__ ehb3,
    float* __restrict__ out, int* __restrict__ bar)
{
    extern __shared__ char smem_raw[];
    const int wg = blockIdx.x, tid = threadIdx.x;
    uint32_t* h0p = hpack;
    uint32_t* h1p = hpack + 32768;
    uint32_t* ht0 = hpack + 65536;
    uint32_t* ht1 = hpack + 98304;

    if (wg >= NGATE){
        // -------- MFMA encoder wg --------
        float* t1 = (float*)smem_raw;          // [16][132]
        float* t2 = t1 + 16*132;               // [16][132]
        const int e = wg - NGATE;              // 0..3
        const s16x8* ehi = (const s16x8*)epack;
        const s16x8* elo = ehi + 288*64;
        const int lane = tid & 63, wv = tid >> 6, c16 = lane & 15;
        float bias1[2], bias2[2], bias3[8];
        #pragma unroll
        for (int nt = 0; nt < 2; nt++){
            bias1[nt] = ehb1[wv*32 + nt*16 + c16];
            bias2[nt] = ehb2[wv*32 + nt*16 + c16];
        }
        #pragma unroll
        for (int nt = 0; nt < 8; nt++)
            bias3[nt] = ehb3[wv*128 + nt*16 + c16];
        for (int t = 0; t < TT; t++){
            enc_mfma(e, h1p, ht1, ehi, elo, bias1, bias2, bias3, t1, t2);
            gbar(bar, NWG*(2*t+1));
            enc_mfma(e, h0p, ht0, ehi, elo, bias1, bias2, bias3, t1, t2);
            gbar(bar, NWG*(2*t+2));
        }
        return;
    }
    // -------- gate wg: 32 gate-columns --------
    s16x8* whl  = (s16x8*)smem_raw;          // [2][56][64] hi-weight frags = 114688 B
    float* glds = (float*)(whl + 7168);      // 64*33 floats
    const int g = wg;
    const s16x8* wp = (const s16x8*)wpack;
    for (int i = tid; i < 7168; i += 256){
        int ng = (i >= 3584) ? 1 : 0;
        int r  = i - ng*3584;
        whl[i] = wp[(long)(2*g+ng)*7168 + r];
    }
    const s16x8* wlo0 = wp + (long)(2*g  )*7168 + 3584;
    const s16x8* wlo1 = wp + (long)(2*g+1)*7168 + 3584;

    const int jloc = tid & 7, bb = tid >> 3;
    const int jcol = g*8 + jloc;
    float bsum0[4], bsum1[4];
    #pragma unroll
    for (int q = 0; q < 4; q++){
        int n = q*512 + jcol;
        bsum0[q] = bih0[n] + bhh0[n];
        bsum1[q] = bih1[n] + bhh1[n];
    }
    float c0reg[2], c1reg[2], h0reg[2] = {0.f,0.f}, h1reg[2] = {0.f,0.f};
    #pragma unroll
    for (int half = 0; half < 2; half++){
        int b = bb + half*32;
        c0reg[half] = c0in[b*HH + jcol];
        c1reg[half] = c0in[32768 + b*HH + jcol];
    }
    __syncthreads();

    for (int t = 0; t < TT; t++){
        gate_phase(0, t, g, tid, whl, glds, wlo0, wlo1,
                   xp, h0p, ht0, bsum0, h0p, c0reg, h0reg, nullptr);
        gbar(bar, NWG*(2*t+1));
        gate_phase(1, t, g, tid, whl, glds, wlo0, wlo1,
                   xp, h0p, ht1, bsum1, h1p, c1reg, h1reg, out);
        gbar(bar, NWG*(2*t+2));
    }
    const long base = (long)BB*TT*HH;
    #pragma unroll
    for (int half = 0; half < 2; half++){
        int b = bb + half*32;
        out[base +                  b*HH + jcol] = h0reg[half];
        out[base + 32768          + b*HH + jcol] = h1reg[half];
        out[base + 65536          + b*HH + jcol] = c0reg[half];
        out[base + 65536 + 32768  + b*HH + jcol] = c1reg[half];
    }
}

// ---------------- launch ----------------
extern "C" void kernel_launch(void* const* d_in, const int* in_sizes, int n_in,
                              void* d_out, int out_size, void* d_ws, size_t ws_size,
                              hipStream_t stream)
{
    const float* input = (const float*)d_in[0];
    const float* h0in  = (const float*)d_in[1];
    const float* c0in  = (const float*)d_in[2];
    const float* Wih0  = (const float*)d_in[3];
    const float* Whh0  = (const float*)d_in[4];
    const float* bih0  = (const float*)d_in[5];
    const float* bhh0  = (const float*)d_in[6];
    const float* Wih1  = (const float*)d_in[7];
    const float* Whh1  = (const float*)d_in[8];
    const float* bih1  = (const float*)d_in[9];
    const float* bhh1  = (const float*)d_in[10];
    const float* eyw1  = (const float*)d_in[11];
    const float* eyb1  = (const float*)d_in[12];
    const float* eyw2  = (const float*)d_in[13];
    const float* eyb2  = (const float*)d_in[14];
    const float* eyw3  = (const float*)d_in[15];
    const float* eyb3  = (const float*)d_in[16];
    const float* ehw1  = (const float*)d_in[17];
    const float* ehb1  = (const float*)d_in[18];
    const float* ehw2  = (const float*)d_in[19];
    const float* ehb2  = (const float*)d_in[20];
    const float* ehw3  = (const float*)d_in[21];
    const float* ehb3  = (const float*)d_in[22];

    float* out = (float*)d_out;
    float* ws  = (float*)d_ws;

    // ws layout (4B units)
    uint32_t* xprime = (uint32_t*)ws;                  // [T][B][I] packed, 33,554,432
    uint32_t* hpack  = (uint32_t*)(ws + 33554432);     // 4 x 32768 (h0,h1,ht0,ht1)
    int*      bar    = (int*)(ws + 33685504);          // own region
    ushort*   wpack  = (ushort*)(ws + 33751104);       // 14,680,064 B
    ushort*   epack  = (ushort*)(ws + 37421120);       // 589,824 B

    hipFuncSetAttribute((const void*)persistent_kernel,
                        hipFuncAttributeMaxDynamicSharedMemorySize, 131072);

    init_state_kernel<<<256, 256, 0, stream>>>(h0in, hpack, bar);
    prep_pack_kernel<<<128*56, 64, 0, stream>>>(Wih0, Whh0, Wih1, Whh1, wpack);
    enc_pack_kernel<<<288, 64, 0, stream>>>(ehw1, ehw2, ehw3, epack);
    ency_kernel<<<4096, 256, 0, stream>>>(input, xprime,
                                          eyw1, eyb1, eyw2, eyb2, eyw3, eyb3);
    enc_only_kernel<<<16, 256, 0, stream>>>(hpack, hpack + 65536,
                                            ehw1, ehb1, ehw2, ehb2, ehw3, ehb3);
    persistent_kernel<<<NWG, 256, 123200, stream>>>(
        xprime, hpack, wpack, epack, c0in,
        bih0, bhh0, bih1, bhh1,
        ehb1, ehb2, ehb3,
        out, bar);
}

// Round 6
// 92947.693 us; speedup vs baseline: 3.3522x; 2.2381x over previous
//
#include <hip/hip_runtime.h>
#include <math.h>
#include <stdint.h>

#define TT 2048
#define BB 64
#define II 256
#define HH 512
#define EHD 128
#define NGATE 64
#define NWG 68

typedef __attribute__((ext_vector_type(8))) short s16x8;
typedef __attribute__((ext_vector_type(4))) float f32x4;
typedef __attribute__((ext_vector_type(4))) uint32_t u32x4;

#define WAITVM(N) asm volatile("s_waitcnt vmcnt(" #N ")" ::: "memory")
// pin VM issue order: compiler memory fence (no instruction) + scheduler fence
#define VMFENCE() do { asm volatile("" ::: "memory"); __builtin_amdgcn_sched_barrier(0); } while(0)

// ---------------- scalar helpers ----------------
__device__ __forceinline__ float dot4(const float4 a, const float4 b){
    return a.x*b.x + a.y*b.y + a.z*b.z + a.w*b.w;
}
__device__ __forceinline__ float sigm(float x){ return 1.0f/(1.0f+expf(-x)); }
__device__ __forceinline__ float leakyf(float x){ return x > 0.0f ? x : 0.01f*x; }
__device__ __forceinline__ float alphaf(float x){
    float p = 1.0f/(1.0f+expf(-x));
    return p/(1.0f-p);
}
__device__ __forceinline__ f32x4 MFMA(s16x8 a, s16x8 b, f32x4 c){
    return __builtin_amdgcn_mfma_f32_16x16x32_bf16(a, b, c, 0, 0, 0);
}

// ---------------- coherent (cross-XCD) access ----------------
__device__ __forceinline__ uint32_t cld_u32(const uint32_t* p){
    return __hip_atomic_load(p, __ATOMIC_RELAXED, __HIP_MEMORY_SCOPE_AGENT);
}
__device__ __forceinline__ uint64_t cld_u64(const uint64_t* p){
    return __hip_atomic_load(p, __ATOMIC_RELAXED, __HIP_MEMORY_SCOPE_AGENT);
}
__device__ __forceinline__ void cst_u32(uint32_t* p, uint32_t v){
    __hip_atomic_store(p, v, __ATOMIC_RELAXED, __HIP_MEMORY_SCOPE_AGENT);
}

// packed bf16 hi/lo pair
__device__ __forceinline__ uint32_t packsplit(float v){
    uint32_t u  = __float_as_uint(v);
    uint32_t hi = u & 0xFFFF0000u;
    float    lo = v - __uint_as_float(hi);
    return hi | (__float_as_uint(lo) >> 16);
}
__device__ __forceinline__ float unpackf(uint32_t w){
    return __uint_as_float(w & 0xFFFF0000u) + __uint_as_float(w << 16);
}

// ---------------- async global->LDS (16B per lane, lane-contiguous src) ----------------
__device__ __forceinline__ void stage16(const void* g, void* l){
    __builtin_amdgcn_global_load_lds(
        (const __attribute__((address_space(1))) void*)g,
        (__attribute__((address_space(3))) void*)l, 16, 0, 0);
}

// ---------------- global barrier (fence-free) ----------------
__device__ __forceinline__ void gbar(int* bar, int target){
    asm volatile("s_waitcnt vmcnt(0)" ::: "memory");
    __syncthreads();
    if (threadIdx.x == 0){
        __hip_atomic_fetch_add(bar, 1, __ATOMIC_RELAXED, __HIP_MEMORY_SCOPE_AGENT);
        while (__hip_atomic_load(bar, __ATOMIC_RELAXED, __HIP_MEMORY_SCOPE_AGENT) < target)
            __builtin_amdgcn_s_sleep(1);
    }
    __syncthreads();
}

// workgroup barrier flavors (avoid __syncthreads' vmcnt(0) drain)
__device__ __forceinline__ void wgbar(){ __builtin_amdgcn_s_barrier(); }
__device__ __forceinline__ void wgbar_lgkm(){
    asm volatile("s_waitcnt lgkmcnt(0)" ::: "memory");
    __builtin_amdgcn_s_barrier();
}

// ---------------- fragment builders ----------------
__device__ __forceinline__ void mk_frag(const uint64_t d[4], s16x8* hi, s16x8* lo){
    union { u32x4 u; s16x8 s; } H, L;
    #pragma unroll
    for (int i = 0; i < 4; i++){
        uint32_t x0 = (uint32_t)d[i], x1 = (uint32_t)(d[i] >> 32);
        H.u[i] = __builtin_amdgcn_perm(x1, x0, 0x07060302u);
        L.u[i] = __builtin_amdgcn_perm(x1, x0, 0x05040100u);
    }
    *hi = H.s; *lo = L.s;
}
__device__ __forceinline__ void pack8(const float* f, s16x8* hi, s16x8* lo){
    union { u32x4 u; s16x8 s; } H, L;
    #pragma unroll
    for (int i = 0; i < 4; i++){
        float a = f[2*i], b = f[2*i+1];
        uint32_t ua = __float_as_uint(a), ub = __float_as_uint(b);
        uint32_t ha = ua & 0xFFFF0000u, hb = ub & 0xFFFF0000u;
        H.u[i] = (ua >> 16) | hb;
        float la = a - __uint_as_float(ha), lb = b - __uint_as_float(hb);
        L.u[i] = (__float_as_uint(la) >> 16) | (__float_as_uint(lb) & 0xFFFF0000u);
    }
    *hi = H.s; *lo = L.s;
}

// ---------------- fp32 encoder block (PROLOGUE ONLY) ----------------
__device__ void enc_h_block(int e, const uint32_t* __restrict__ hsrc,
                            uint32_t* __restrict__ htil,
                            const float* __restrict__ w1, const float* __restrict__ b1,
                            const float* __restrict__ w2, const float* __restrict__ b2,
                            const float* __restrict__ w3, const float* __restrict__ b3,
                            float* smem)
{
    float* hlds = smem;              // [4][516]
    float* t1   = smem + 4*516;      // [4][132]
    float* t2   = t1 + 4*132;        // [4][132]
    const int tid = threadIdx.x;
    const int r0 = e * 4;
    #pragma unroll
    for (int i = 0; i < 8; i++){
        int el = tid + i*256;
        int rr = el >> 9, k = el & 511;
        hlds[rr*516 + k] = unpackf(cld_u32(hsrc + (r0+rr)*HH + k));
    }
    __syncthreads();
    const int cc = tid & 63;
    const int rr = (tid >> 6) & 3;
    for (int cb = 0; cb < 2; cb++){
        int c = cc + cb*64;
        const float* wr = w1 + c*HH;
        const float* xr = hlds + rr*516;
        float a0 = b1[c], a1 = 0.f;
        #pragma unroll 8
        for (int k = 0; k < HH; k += 8){
            a0 += dot4(*(const float4*)(xr+k),   *(const float4*)(wr+k));
            a1 += dot4(*(const float4*)(xr+k+4), *(const float4*)(wr+k+4));
        }
        t1[rr*132 + c] = leakyf(a0 + a1);
    }
    __syncthreads();
    for (int cb = 0; cb < 2; cb++){
        int c = cc + cb*64;
        const float* wr = w2 + c*EHD;
        const float* xr = t1 + rr*132;
        float a0 = b2[c], a1 = 0.f;
        #pragma unroll 4
        for (int k = 0; k < EHD; k += 8){
            a0 += dot4(*(const float4*)(xr+k),   *(const float4*)(wr+k));
            a1 += dot4(*(const float4*)(xr+k+4), *(const float4*)(wr+k+4));
        }
        t2[rr*132 + c] = leakyf(a0 + a1);
    }
    __syncthreads();
    for (int cb = 0; cb < 8; cb++){
        int c = cc + cb*64;
        const float* wr = w3 + c*EHD;
        const float* xr = t2 + rr*132;
        float a0 = b3[c], a1 = 0.f;
        #pragma unroll 4
        for (int k = 0; k < EHD; k += 8){
            a0 += dot4(*(const float4*)(xr+k),   *(const float4*)(wr+k));
            a1 += dot4(*(const float4*)(xr+k+4), *(const float4*)(wr+k+4));
        }
        float a = alphaf(a0 + a1);
        cst_u32(htil + (r0+rr)*HH + c, packsplit(hlds[rr*516 + c] * a));
    }
    __syncthreads();
}

__global__ __launch_bounds__(256) void enc_only_kernel(
    const uint32_t* __restrict__ hsrc, uint32_t* __restrict__ htil,
    const float* __restrict__ w1, const float* __restrict__ b1,
    const float* __restrict__ w2, const float* __restrict__ b2,
    const float* __restrict__ w3, const float* __restrict__ b3)
{
    __shared__ float smem[3120];
    enc_h_block(blockIdx.x, hsrc, htil, w1, b1, w2, b2, w3, b3, smem);
}

// ---------------- x' = input * alpha_y(input): packed, [T][B][I] ----------------
__global__ __launch_bounds__(256) void ency_kernel(
    const float* __restrict__ xin, uint32_t* __restrict__ xprime,
    const float* __restrict__ w1, const float* __restrict__ b1,
    const float* __restrict__ w2, const float* __restrict__ b2,
    const float* __restrict__ w3, const float* __restrict__ b3)
{
    __shared__ float t1[32*128];
    __shared__ float t2[32*128];
    const long m0 = (long)blockIdx.x * 32;
    const int tid = threadIdx.x;
    const int cc = tid & 63;
    const int rr = tid >> 6;
    for (int cb = 0; cb < 2; cb++){
        int c = cc + cb*64;
        const float* wr = w1 + c*II;
        for (int q = 0; q < 8; q++){
            int r = rr*8 + q;
            const float* xr = xin + (m0 + r)*II;
            float a0 = b1[c], a1 = 0.f;
            #pragma unroll 8
            for (int k = 0; k < II; k += 8){
                a0 += dot4(*(const float4*)(xr+k),   *(const float4*)(wr+k));
                a1 += dot4(*(const float4*)(xr+k+4), *(const float4*)(wr+k+4));
            }
            t1[r*128 + c] = leakyf(a0 + a1);
        }
    }
    __syncthreads();
    for (int cb = 0; cb < 2; cb++){
        int c = cc + cb*64;
        const float* wr = w2 + c*EHD;
        for (int q = 0; q < 8; q++){
            int r = rr*8 + q;
            const float* xr = t1 + r*128;
            float a0 = b2[c], a1 = 0.f;
            #pragma unroll 4
            for (int k = 0; k < EHD; k += 8){
                a0 += dot4(*(const float4*)(xr+k),   *(const float4*)(wr+k));
                a1 += dot4(*(const float4*)(xr+k+4), *(const float4*)(wr+k+4));
            }
            t2[r*128 + c] = leakyf(a0 + a1);
        }
    }
    __syncthreads();
    for (int cb = 0; cb < 4; cb++){
        int c = cc + cb*64;
        const float* wr = w3 + c*EHD;
        for (int q = 0; q < 8; q++){
            int r = rr*8 + q;
            const float* xr = t2 + r*128;
            float a0 = b3[c], a1 = 0.f;
            #pragma unroll 4
            for (int k = 0; k < EHD; k += 8){
                a0 += dot4(*(const float4*)(xr+k),   *(const float4*)(wr+k));
                a1 += dot4(*(const float4*)(xr+k+4), *(const float4*)(wr+k+4));
            }
            float a = alphaf(a0 + a1);
            long m = m0 + r;                       // m = b*TT + t
            long b = m >> 11, t = m & 2047;
            xprime[((long)t*BB + b)*II + c] = packsplit(xin[m*II + c] * a);
        }
    }
}

// ---------------- gate weight packing ----------------
__global__ __launch_bounds__(64) void prep_pack_kernel(
    const float* __restrict__ Wih0, const float* __restrict__ Whh0,
    const float* __restrict__ Wih1, const float* __restrict__ Whh1,
    ushort* __restrict__ wpack)
{
    const int b = blockIdx.x;          // 128*56
    const int lane = threadIdx.x;
    const int g4 = b / 56, kts = b % 56;
    const int layer = (kts >= 24) ? 1 : 0;
    const int kt = layer ? (kts - 24) : kts;
    const int c = lane & 15;
    const int gate = c >> 2, uu = c & 3;
    const int n = gate*512 + g4*4 + uu;
    const int k = kt*32 + (lane >> 4)*8;
    const float* src;
    if (!layer){
        if (k < 256) src = Wih0 + (long)n*II + k;
        else         src = Whh0 + (long)n*HH + (k - 256);
    } else {
        if (k < 512) src = Wih1 + (long)n*HH + k;
        else         src = Whh1 + (long)n*HH + (k - 512);
    }
    ushort hi[8], lo[8];
    #pragma unroll
    for (int j = 0; j < 8; j++){
        float v = src[j];
        uint32_t u = __float_as_uint(v);
        hi[j] = (ushort)(u >> 16);
        float hf = __uint_as_float(u & 0xFFFF0000u);
        lo[j] = (ushort)(__float_as_uint(v - hf) >> 16);
    }
    long bhi = ((long)g4*7168 + kts*64 + lane) * 8;
    long blo = bhi + (long)3584*8;
    #pragma unroll
    for (int j = 0; j < 8; j++){ wpack[bhi + j] = hi[j]; wpack[blo + j] = lo[j]; }
}

// ---------------- encoder weight packing ----------------
__global__ __launch_bounds__(64) void enc_pack_kernel(
    const float* __restrict__ w1, const float* __restrict__ w2,
    const float* __restrict__ w3, ushort* __restrict__ epack)
{
    const int f = blockIdx.x;      // 0..287
    const int lane = threadIdx.x;
    const int c = lane & 15, kq = lane >> 4;
    const float* src;
    if (f < 128){
        int nt = f >> 4, kt = f & 15;
        src = w1 + (long)(nt*16 + c)*HH + kt*32 + kq*8;
    } else if (f < 160){
        int q = f - 128; int nt = q >> 2, kt = q & 3;
        src = w2 + (long)(nt*16 + c)*EHD + kt*32 + kq*8;
    } else {
        int q = f - 160; int nt = q >> 2, kt = q & 3;
        src = w3 + (long)(nt*16 + c)*EHD + kt*32 + kq*8;
    }
    long off = ((long)f*64 + lane)*8;
    #pragma unroll
    for (int j = 0; j < 8; j++){
        float v = src[j];
        uint32_t u = __float_as_uint(v);
        epack[off + j] = (ushort)(u >> 16);
        float hf = __uint_as_float(u & 0xFFFF0000u);
        epack[off + 147456 + j] = (ushort)(__float_as_uint(v - hf) >> 16);
    }
}

// ---------------- init ----------------
__global__ __launch_bounds__(256) void init_state_kernel(
    const float* __restrict__ h0, uint32_t* __restrict__ hpack, int* __restrict__ bar)
{
    int i = blockIdx.x*256 + threadIdx.x;
    hpack[i] = packsplit(h0[i]);
    if (i == 0) bar[0] = 0;
}

// ---------------- gate helpers ----------------
struct Accs { f32x4 a1, a2, b1, b2; };

// all-atomic A loads: exactly 8 non-mergeable VM ops per call
template<int PHASE>
__device__ __forceinline__ void gate_aload(int c, int t, int brow, int kq,
    const uint32_t* __restrict__ xp, const uint32_t* __restrict__ h0p,
    const uint32_t* __restrict__ htilp, uint64_t* d)
{
    #pragma unroll
    for (int ktl = 0; ktl < 2; ktl++){
        const int kt = c*2 + ktl;
        const uint64_t* p;
        if (PHASE == 0){
            if (kt < 8) p = (const uint64_t*)(xp + ((long)t*BB + brow)*II) + kt*16 + kq*4;
            else        p = (const uint64_t*)(htilp + (long)brow*HH) + (kt-8)*16 + kq*4;
        } else {
            if (kt < 16) p = (const uint64_t*)(h0p + (long)brow*HH) + kt*16 + kq*4;
            else         p = (const uint64_t*)(htilp + (long)brow*HH) + (kt-16)*16 + kq*4;
        }
        #pragma unroll
        for (int i=0;i<4;i++) d[ktl*4+i] = cld_u64(p+i);
    }
}

// ---------------- gate phase: DMA-staged lo-weights, pipelined A ----------------
template<int PHASE>
__device__ __forceinline__ void gate_phase(
    int t, int g, int tid,
    const s16x8* __restrict__ whl, char* __restrict__ wbuf,
    const s16x8* __restrict__ wlo0, const s16x8* __restrict__ wlo1,
    const uint32_t* __restrict__ xp,
    const uint32_t* __restrict__ h0p,
    const uint32_t* __restrict__ htilp,
    const float* bsum, uint32_t* __restrict__ hdst,
    float creg[2], float hreg[2], float* __restrict__ yout)
{
    const int lane = tid & 63;
    const int wv   = tid >> 6;
    const int brow = wv*16 + (lane & 15);
    const int kq   = lane >> 4;
    constexpr int NCH = PHASE ? 16 : 12;
    constexpr int KT0 = PHASE ? 24 : 0;

    const int sktl = wv >> 1, sng = wv & 1;          // per-wave staging role
    const s16x8* swsrc = sng ? wlo1 : wlo0;
    const int sfi = sktl*2 + sng;

    Accs ac = {};
    uint64_t dA[2][8];

    // prologue: S0, A0, S1, A1 — order pinned so WAITVM counts hold
    stage16((const char*)(swsrc + (KT0 + 0 + sktl)*64) + lane*16, wbuf + 0*4096 + sfi*1024);
    VMFENCE();
    gate_aload<PHASE>(0, t, brow, kq, xp, h0p, htilp, dA[0]);
    VMFENCE();
    stage16((const char*)(swsrc + (KT0 + 2 + sktl)*64) + lane*16, wbuf + 1*4096 + sfi*1024);
    VMFENCE();
    gate_aload<PHASE>(1, t, brow, kq, xp, h0p, htilp, dA[1]);
    VMFENCE();

    #pragma unroll
    for (int c = 0; c < NCH; c++){
        // queue per iter (pinned): [S, A(8)] = 9 ops; drain exactly the
        // iteration issued two ago -> slot c + dA[c&1] arrived.
        if (c < NCH-1) { WAITVM(9); } else { WAITVM(0); }
        wgbar();                                      // all waves' S_c arrived
        s16x8 ah0, al0, ah1, al1;
        mk_frag(&dA[c&1][0], &ah0, &al0);
        mk_frag(&dA[c&1][4], &ah1, &al1);
        if (c + 2 < NCH){
            stage16((const char*)(swsrc + (KT0 + (c+2)*2 + sktl)*64) + lane*16,
                    wbuf + ((c+2)%3)*4096 + sfi*1024);
            VMFENCE();
            gate_aload<PHASE>(c+2, t, brow, kq, xp, h0p, htilp, dA[c&1]);
            VMFENCE();
        }
        const s16x8* sb = (const s16x8*)(wbuf + (c%3)*4096);
        #pragma unroll
        for (int ktl = 0; ktl < 2; ktl++){
            const int ktg = KT0 + c*2 + ktl;
            s16x8 ah = ktl ? ah1 : ah0;
            s16x8 al = ktl ? al1 : al0;
            { s16x8 B1 = whl[ktg*64 + lane];
              s16x8 B2 = sb[(ktl*2+0)*64 + lane];
              ac.a1 = MFMA(ah, B1, ac.a1);
              ac.a2 = MFMA(al, B1, ac.a2);
              ac.a2 = MFMA(ah, B2, ac.a2); }
            { s16x8 B1 = whl[3584 + ktg*64 + lane];
              s16x8 B2 = sb[(ktl*2+1)*64 + lane];
              ac.b1 = MFMA(ah, B1, ac.b1);
              ac.b2 = MFMA(al, B1, ac.b2);
              ac.b2 = MFMA(ah, B2, ac.b2); }
        }
    }
    wgbar_lgkm();                                    // all slot reads done
    float* glds = (float*)wbuf;                      // union with staging ring
    {
        f32x4 caf = ac.a1 + ac.a2;
        f32x4 cbf = ac.b1 + ac.b2;
        const int r0 = wv*16 + (lane>>4)*4;
        const int c16 = lane & 15;
        #pragma unroll
        for (int i = 0; i < 4; i++){
            glds[(r0+i)*33 + c16]      = caf[i];
            glds[(r0+i)*33 + 16 + c16] = cbf[i];
        }
    }
    wgbar_lgkm();
    {
        const int jloc = tid & 7, bb2 = tid >> 3;
        const int ng = jloc >> 2, uu = jloc & 3;
        const int jcol = g*8 + jloc;
        #pragma unroll
        for (int half = 0; half < 2; half++){
            int b = bb2 + half*32;
            float gi = glds[b*33 + ng*16 + 0  + uu] + bsum[0];
            float gf = glds[b*33 + ng*16 + 4  + uu] + bsum[1];
            float gg = glds[b*33 + ng*16 + 8  + uu] + bsum[2];
            float go = glds[b*33 + ng*16 + 12 + uu] + bsum[3];
            float cn = sigm(gf)*creg[half] + sigm(gi)*tanhf(gg);
            float hn = sigm(go)*tanhf(cn);
            creg[half] = cn; hreg[half] = hn;
            cst_u32(hdst + b*HH + jcol, packsplit(hn));
            if (yout) yout[((long)b*TT + t)*HH + jcol] = hn;
        }
    }
}

// ---------------- encoder staging (8 frags/chunk, per-wave private ring) ----------------
__device__ __forceinline__ void enc_stage(int c, int wv, int lane,
                                          const char* __restrict__ epb, char* __restrict__ ebuf)
{
    char* slot = ebuf + (c%3)*8192;
    if (c < 8){
        #pragma unroll
        for (int ktl=0;ktl<2;ktl++)
        #pragma unroll
        for (int nt=0;nt<2;nt++)
        #pragma unroll
        for (int hl=0;hl<2;hl++){
            int f = (wv*2+nt)*16 + (c*2+ktl);
            long fidx = hl ? (288+f) : f;
            stage16(epb + fidx*1024 + lane*16, slot + (ktl*4+nt*2+hl)*1024);
        }
    } else if (c < 10){
        #pragma unroll
        for (int ktl=0;ktl<2;ktl++)
        #pragma unroll
        for (int nt=0;nt<2;nt++)
        #pragma unroll
        for (int hl=0;hl<2;hl++){
            int f = 128 + (wv*2+nt)*4 + ((c-8)*2+ktl);
            long fidx = hl ? (288+f) : f;
            stage16(epb + fidx*1024 + lane*16, slot + (ktl*4+nt*2+hl)*1024);
        }
    } else {
        int nt = c - 10;
        #pragma unroll
        for (int kt=0;kt<4;kt++)
        #pragma unroll
        for (int hl=0;hl<2;hl++){
            int f = 160 + (wv*8+nt)*4 + kt;
            long fidx = hl ? (288+f) : f;
            stage16(epb + fidx*1024 + lane*16, slot + (kt*2+hl)*1024);
        }
    }
}

// ---------------- encoder phase (MFMA, DMA-staged weights) ----------------
__device__ void enc_phase(
    int e, const uint32_t* __restrict__ hsrc, uint32_t* __restrict__ htil,
    const char* __restrict__ epb, char* __restrict__ ebuf,
    const float bias1[2], const float bias2[2], const float bias3[8],
    float* __restrict__ t1, float* __restrict__ t2)
{
    const int tid = threadIdx.x;
    const int lane = tid & 63, wv = tid >> 6;
    const int c16 = lane & 15, kq = lane >> 4;
    const int r0 = e * 16;

    // H values for layer-3 scaling (32 cld_u32), issued first
    uint32_t hv[32];
    #pragma unroll
    for (int nt=0;nt<8;nt++)
      #pragma unroll
      for (int i=0;i<4;i++)
        hv[nt*4+i] = cld_u32(hsrc + (long)(r0+kq*4+i)*HH + wv*128 + nt*16 + c16);
    VMFENCE();

    // A first half (kt 0..7): 32 atomic u64 loads
    const uint64_t* hp = (const uint64_t*)(hsrc + (long)(r0 + c16)*HH) + kq*4;
    uint64_t dA[32];
    #pragma unroll
    for (int kt=0;kt<8;kt++)
      #pragma unroll
      for (int i=0;i<4;i++)
        dA[kt*4+i] = cld_u64(hp + kt*16 + i);
    VMFENCE();

    enc_stage(0, wv, lane, epb, ebuf);
    VMFENCE();
    enc_stage(1, wv, lane, epb, ebuf);
    VMFENCE();
    WAITVM(16);                     // queue: [hv(32),A0(32),S0(8),S1(8)] -> leaves S0,S1
    s16x8 ah1[8], al1[8], ah2[8], al2[8];
    #pragma unroll
    for (int kt=0;kt<8;kt++) mk_frag(&dA[kt*4], &ah1[kt], &al1[kt]);
    // A second half (kt 8..15)
    #pragma unroll
    for (int kt=0;kt<8;kt++)
      #pragma unroll
      for (int i=0;i<4;i++)
        dA[kt*4+i] = cld_u64(hp + (kt+8)*16 + i);
    VMFENCE();

    f32x4 p1[2] = {{0,0,0,0},{0,0,0,0}};
    f32x4 p2[2] = {{0,0,0,0},{0,0,0,0}};
    // ---- layer 1: chunks 0..7 ----
    #pragma unroll
    for (int c=0;c<8;c++){
        if (c < 2) { WAITVM(40); } else { WAITVM(8); }
        const s16x8* sb = (const s16x8*)(ebuf + (c%3)*8192);
        #pragma unroll
        for (int ktl=0;ktl<2;ktl++){
            const int kt = c*2 + ktl;
            s16x8 ah = (kt<8) ? ah1[kt&7] : ah2[kt&7];
            s16x8 al = (kt<8) ? al1[kt&7] : al2[kt&7];
            #pragma unroll
            for (int nt=0;nt<2;nt++){
                s16x8 bh = sb[(ktl*4+nt*2+0)*64 + lane];
                s16x8 bl = sb[(ktl*4+nt*2+1)*64 + lane];
                p1[nt] = MFMA(ah, bh, p1[nt]);
                p2[nt] = MFMA(al, bh, p2[nt]);
                p2[nt] = MFMA(ah, bl, p2[nt]);
            }
        }
        enc_stage(c+2, wv, lane, epb, ebuf);
        VMFENCE();
        if (c == 3){   // A-half1 drained by c=2's WAITVM(8)
            #pragma unroll
            for (int kt=0;kt<8;kt++) mk_frag(&dA[kt*4], &ah2[kt], &al2[kt]);
        }
    }
    #pragma unroll
    for (int nt=0;nt<2;nt++){
        f32x4 cc = p1[nt] + p2[nt];
        const int n = wv*32 + nt*16 + c16;
        #pragma unroll
        for (int i=0;i<4;i++) t1[(kq*4+i)*132 + n] = leakyf(cc[i] + bias1[nt]);
    }
    wgbar_lgkm();
    // ---- layer 2: chunks 8,9 ----
    s16x8 a2h[4], a2l[4];
    #pragma unroll
    for (int kt=0;kt<4;kt++) pack8(t1 + c16*132 + kt*32 + kq*8, &a2h[kt], &a2l[kt]);
    f32x4 q1[2] = {{0,0,0,0},{0,0,0,0}};
    f32x4 q2[2] = {{0,0,0,0},{0,0,0,0}};
    #pragma unroll
    for (int c=8;c<10;c++){
        WAITVM(8);
        const s16x8* sb = (const s16x8*)(ebuf + (c%3)*8192);
        #pragma unroll
        for (int ktl=0;ktl<2;ktl++){
            const int kt = (c-8)*2 + ktl;
            #pragma unroll
            for (int nt=0;nt<2;nt++){
                s16x8 bh = sb[(ktl*4+nt*2+0)*64 + lane];
                s16x8 bl = sb[(ktl*4+nt*2+1)*64 + lane];
                q1[nt] = MFMA(a2h[kt], bh, q1[nt]);
                q2[nt] = MFMA(a2l[kt], bh, q2[nt]);
                q2[nt] = MFMA(a2h[kt], bl, q2[nt]);
            }
        }
        enc_stage(c+2, wv, lane, epb, ebuf);
        VMFENCE();
    }
    #pragma unroll
    for (int nt=0;nt<2;nt++){
        f32x4 cc = q1[nt] + q2[nt];
        const int n = wv*32 + nt*16 + c16;
        #pragma unroll
        for (int i=0;i<4;i++) t2[(kq*4+i)*132 + n] = leakyf(cc[i] + bias2[nt]);
    }
    wgbar_lgkm();
    // ---- layer 3: chunks 10..17 ----
    s16x8 a3h[4], a3l[4];
    #pragma unroll
    for (int kt=0;kt<4;kt++) pack8(t2 + c16*132 + kt*32 + kq*8, &a3h[kt], &a3l[kt]);
    float av[8][4];
    #pragma unroll
    for (int c=10;c<18;c++){
        if (c < 17) { WAITVM(8); } else { WAITVM(0); }
        const int nt = c - 10;
        const s16x8* sb = (const s16x8*)(ebuf + (c%3)*8192);
        f32x4 s1 = {0,0,0,0}, s2 = {0,0,0,0};
        #pragma unroll
        for (int kt=0;kt<4;kt++){
            s16x8 bh = sb[(kt*2+0)*64 + lane];
            s16x8 bl = sb[(kt*2+1)*64 + lane];
            s1 = MFMA(a3h[kt], bh, s1);
            s2 = MFMA(a3l[kt], bh, s2);
            s2 = MFMA(a3h[kt], bl, s2);
        }
        f32x4 cc = s1 + s2;
        #pragma unroll
        for (int i=0;i<4;i++) av[nt][i] = alphaf(cc[i] + bias3[nt]);
        if (c + 2 < 18){
            enc_stage(c+2, wv, lane, epb, ebuf);
            VMFENCE();
        }
    }
    // stores
    #pragma unroll
    for (int nt=0;nt<8;nt++)
      #pragma unroll
      for (int i=0;i<4;i++){
        const int row = r0 + kq*4 + i;
        const int n = wv*128 + nt*16 + c16;
        cst_u32(htil + (long)row*HH + n, packsplit(unpackf(hv[nt*4+i]) * av[nt][i]));
      }
}

// ---------------- persistent kernel ----------------
__global__ __launch_bounds__(256, 1) void persistent_kernel(
    const uint32_t* __restrict__ xp,
    uint32_t* __restrict__ hpack,
    const ushort* __restrict__ wpack,
    const ushort* __restrict__ epack,
    const float* __restrict__ c0in,
    const float* __restrict__ bih0, const float* __restrict__ bhh0,
    const float* __restrict__ bih1, const float* __restrict__ bhh1,
    const float* __restrict__ ehb1, const float* __restrict__ ehb2,
    const float* __restrict__ ehb3,
    float* __restrict__ out, int* __restrict__ bar)
{
    extern __shared__ char smem_raw[];
    const int wg = blockIdx.x, tid = threadIdx.x;
    uint32_t* h0p = hpack;
    uint32_t* h1p = hpack + 32768;
    uint32_t* ht0 = hpack + 65536;
    uint32_t* ht1 = hpack + 98304;

    if (wg >= NGATE){
        // -------- encoder wg (DMA-staged MFMA) --------
        char* ebuf = smem_raw + (tid>>6)*24576;       // per-wave 3x8KB ring
        float* t1 = (float*)(smem_raw + 98304);       // [16][132]
        float* t2 = t1 + 16*132;
        const int e = wg - NGATE;                     // 0..3
        const char* epb = (const char*)epack;
        const int lane = tid & 63, wv = tid >> 6, c16 = lane & 15;
        float bias1[2], bias2[2], bias3[8];
        #pragma unroll
        for (int nt = 0; nt < 2; nt++){
            bias1[nt] = ehb1[wv*32 + nt*16 + c16];
            bias2[nt] = ehb2[wv*32 + nt*16 + c16];
        }
        #pragma unroll
        for (int nt = 0; nt < 8; nt++)
            bias3[nt] = ehb3[wv*128 + nt*16 + c16];
        WAITVM(0);
        __syncthreads();
        for (int t = 0; t < TT; t++){
            enc_phase(e, h1p, ht1, epb, ebuf, bias1, bias2, bias3, t1, t2);
            gbar(bar, NWG*(2*t+1));
            enc_phase(e, h0p, ht0, epb, ebuf, bias1, bias2, bias3, t1, t2);
            gbar(bar, NWG*(2*t+2));
        }
        return;
    }
    // -------- gate wg: 32 gate-columns --------
    s16x8* whl = (s16x8*)smem_raw;                   // 7168 frags = 114688 B
    char*  wbuf = smem_raw + 114688;                 // 3x4KB ring (union glds)
    const int g = wg;
    const s16x8* wp = (const s16x8*)wpack;
    for (int i = tid; i < 7168; i += 256){
        int ng = (i >= 3584) ? 1 : 0;
        int r  = i - ng*3584;
        whl[i] = wp[(long)(2*g+ng)*7168 + r];
    }
    const s16x8* wlo0 = wp + (long)(2*g  )*7168 + 3584;
    const s16x8* wlo1 = wp + (long)(2*g+1)*7168 + 3584;

    const int jloc = tid & 7, bb2 = tid >> 3;
    const int jcol = g*8 + jloc;
    float bsum0[4], bsum1[4];
    #pragma unroll
    for (int q = 0; q < 4; q++){
        int n = q*512 + jcol;
        bsum0[q] = bih0[n] + bhh0[n];
        bsum1[q] = bih1[n] + bhh1[n];
    }
    float c0reg[2], c1reg[2], h0reg[2] = {0.f,0.f}, h1reg[2] = {0.f,0.f};
    #pragma unroll
    for (int half = 0; half < 2; half++){
        int b = bb2 + half*32;
        c0reg[half] = c0in[b*HH + jcol];
        c1reg[half] = c0in[32768 + b*HH + jcol];
    }
    WAITVM(0);
    __syncthreads();

    for (int t = 0; t < TT; t++){
        gate_phase<0>(t, g, tid, whl, wbuf, wlo0, wlo1,
                      xp, h0p, ht0, bsum0, h0p, c0reg, h0reg, nullptr);
        gbar(bar, NWG*(2*t+1));
        gate_phase<1>(t, g, tid, whl, wbuf, wlo0, wlo1,
                      xp, h0p, ht1, bsum1, h1p, c1reg, h1reg, out);
        gbar(bar, NWG*(2*t+2));
    }
    const long base = (long)BB*TT*HH;
    #pragma unroll
    for (int half = 0; half < 2; half++){
        int b = bb2 + half*32;
        out[base +                  b*HH + jcol] = h0reg[half];
        out[base + 32768          + b*HH + jcol] = h1reg[half];
        out[base + 65536          + b*HH + jcol] = c0reg[half];
        out[base + 65536 + 32768  + b*HH + jcol] = c1reg[half];
    }
}

// ---------------- launch ----------------
extern "C" void kernel_launch(void* const* d_in, const int* in_sizes, int n_in,
                              void* d_out, int out_size, void* d_ws, size_t ws_size,
                              hipStream_t stream)
{
    const float* input = (const float*)d_in[0];
    const float* h0in  = (const float*)d_in[1];
    const float* c0in  = (const float*)d_in[2];
    const float* Wih0  = (const float*)d_in[3];
    const float* Whh0  = (const float*)d_in[4];
    const float* bih0  = (const float*)d_in[5];
    const float* bhh0  = (const float*)d_in[6];
    const float* Wih1  = (const float*)d_in[7];
    const float* Whh1  = (const float*)d_in[8];
    const float* bih1  = (const float*)d_in[9];
    const float* bhh1  = (const float*)d_in[10];
    const float* eyw1  = (const float*)d_in[11];
    const float* eyb1  = (const float*)d_in[12];
    const float* eyw2  = (const float*)d_in[13];
    const float* eyb2  = (const float*)d_in[14];
    const float* eyw3  = (const float*)d_in[15];
    const float* eyb3  = (const float*)d_in[16];
    const float* ehw1  = (const float*)d_in[17];
    const float* ehb1  = (const float*)d_in[18];
    const float* ehw2  = (const float*)d_in[19];
    const float* ehb2  = (const float*)d_in[20];
    const float* ehw3  = (const float*)d_in[21];
    const float* ehb3  = (const float*)d_in[22];

    float* out = (float*)d_out;
    float* ws  = (float*)d_ws;

    // ws layout (4B units)
    uint32_t* xprime = (uint32_t*)ws;                  // [T][B][I] packed
    uint32_t* hpack  = (uint32_t*)(ws + 33554432);     // h0,h1,ht0,ht1
    int*      bar    = (int*)(ws + 33685504);
    ushort*   wpack  = (ushort*)(ws + 33751104);       // 14,680,064 B
    ushort*   epack  = (ushort*)(ws + 37421120);       // 589,824 B

    hipFuncSetAttribute((const void*)persistent_kernel,
                        hipFuncAttributeMaxDynamicSharedMemorySize, 131072);

    init_state_kernel<<<256, 256, 0, stream>>>(h0in, hpack, bar);
    prep_pack_kernel<<<128*56, 64, 0, stream>>>(Wih0, Whh0, Wih1, Whh1, wpack);
    enc_pack_kernel<<<288, 64, 0, stream>>>(ehw1, ehw2, ehw3, epack);
    ency_kernel<<<4096, 256, 0, stream>>>(input, xprime,
                                          eyw1, eyb1, eyw2, eyb2, eyw3, eyb3);
    enc_only_kernel<<<16, 256, 0, stream>>>(hpack, hpack + 65536,
                                            ehw1, ehb1, ehw2, ehb2, ehw3, ehb3);
    persistent_kernel<<<NWG, 256, 126976, stream>>>(
        xprime, hpack, wpack, epack, c0in,
        bih0, bhh0, bih1, bhh1,
        ehb1, ehb2, ehb3,
        out, bar);
}